// Round 1
// baseline (1337.860 us; speedup 1.0000x reference)
//
#include <hip/hip_runtime.h>
#include <math.h>

// KSpaceResampling: type-2 NUDFT -> ramp weights -> type-1 adjoint -> abs
// Shapes: x [B=2,H=192,W=192,C=2] fp32; points [49152,2]; weights [49152]
// out [2,192,192,2] fp32.
//
// Exploits (exact math, fp32-noise-level deviation from reference):
//  * Hermitian symmetry: x real => k(v, 384-t) = conj(k(v,t)); forward computes
//    t in [0,192] only; adjoint pairs contribute 2*Re(K cis(phi)).
//  * phi_t = r_t * (cos(th)*nh + sin(th)*nw) is arithmetic in t (and in h, w)
//    => complex rotor recurrence instead of per-element sincos.

#define HH 192
#define WW 192
#define NVIEWS 128
#define NSAMP 384
#define NPIX (HH*WW)      // 36864
#define HALFT 193         // stored t = 0..192
#define NSPLIT 4          // forward h-range splits
#define NCHUNK 4          // adjoint view chunks (32 views each)

__device__ __forceinline__ void rot(float& cr, float& ci, float dr, float di) {
  float nr = cr*dr - ci*di;
  float ni = cr*di + ci*dr;
  cr = nr; ci = ni;
}

// k[cb, v, t] partial over an h-quarter.  cb = b*2 + c.
// thread = t (0..191), block = (v, split). t=192 (DC) handled by dc_kernel.
__global__ __launch_bounds__(192) void fwd_kernel(
    const float* __restrict__ x, const float* __restrict__ points,
    float* __restrict__ kpart) {
  const int v = blockIdx.x;
  const int split = blockIdx.y;
  const int t = threadIdx.x;                 // 0..191
  const int m = v*NSAMP + t;
  const float kx = points[2*m+0];
  const float ky = points[2*m+1];
  const int h0 = split*48;

  float kr[4] = {0,0,0,0}, ki[4] = {0,0,0,0};
  // cis(-ky*(w-96)) state at w=0 and its per-w rotor
  float cyr, cyi; __sincosf(96.0f*ky, &cyi, &cyr);
  float dyr, dyi; __sincosf(-ky, &dyi, &dyr);
  // cis(-kx*(h-96)) start at h=h0 and per-h rotor (constant across wp)
  float cx0r, cx0i; __sincosf(kx*(float)(96-h0), &cx0i, &cx0r);
  float dxr, dxi; __sincosf(-kx, &dxi, &dxr);

  for (int wp = 0; wp < 96; ++wp) {
    const int w0 = wp*2;
    float g0r[4]={0,0,0,0}, g0i[4]={0,0,0,0};   // [cb] at w0
    float g1r[4]={0,0,0,0}, g1i[4]={0,0,0,0};   // [cb] at w0+1
    float cxr = cx0r, cxi = cx0i;
    const float* p0 = x + (h0*WW + w0)*2;            // b=0
    const float* p1 = p0 + HH*WW*2;                  // b=1
    #pragma unroll 4
    for (int h = 0; h < 48; ++h) {
      // float4 = (w0,c0),(w0,c1),(w1,c0),(w1,c1) — wave-uniform address
      float4 a = *(const float4*)(p0 + h*(WW*2));
      float4 b = *(const float4*)(p1 + h*(WW*2));
      g0r[0] += a.x*cxr; g0i[0] += a.x*cxi;
      g0r[1] += a.y*cxr; g0i[1] += a.y*cxi;
      g1r[0] += a.z*cxr; g1i[0] += a.z*cxi;
      g1r[1] += a.w*cxr; g1i[1] += a.w*cxi;
      g0r[2] += b.x*cxr; g0i[2] += b.x*cxi;
      g0r[3] += b.y*cxr; g0i[3] += b.y*cxi;
      g1r[2] += b.z*cxr; g1i[2] += b.z*cxi;
      g1r[3] += b.w*cxr; g1i[3] += b.w*cxi;
      rot(cxr, cxi, dxr, dxi);
    }
    #pragma unroll
    for (int cb = 0; cb < 4; ++cb) {
      kr[cb] += g0r[cb]*cyr - g0i[cb]*cyi;
      ki[cb] += g0r[cb]*cyi + g0i[cb]*cyr;
    }
    rot(cyr, cyi, dyr, dyi);
    #pragma unroll
    for (int cb = 0; cb < 4; ++cb) {
      kr[cb] += g1r[cb]*cyr - g1i[cb]*cyi;
      ki[cb] += g1r[cb]*cyi + g1i[cb]*cyr;
    }
    rot(cyr, cyi, dyr, dyi);
  }
  float* o = kpart + (((split*NVIEWS + v)*192 + t)*4)*2;
  #pragma unroll
  for (int cb = 0; cb < 4; ++cb) { o[2*cb] = kr[cb]; o[2*cb+1] = ki[cb]; }
}

// DC sample (t=192, r=0): k = sum(x) per cb, exactly real.
__global__ __launch_bounds__(256) void dc_kernel(
    const float* __restrict__ x, float* __restrict__ dcsum) {
  const int tid = threadIdx.x;
  float s0=0.f, s1=0.f, s2=0.f, s3=0.f;
  for (int i = tid; i < NPIX; i += 256) {
    float2 a = *(const float2*)(x + i*2);           // b0: (c0,c1)
    float2 b = *(const float2*)(x + HH*WW*2 + i*2); // b1
    s0 += a.x; s1 += a.y; s2 += b.x; s3 += b.y;
  }
  #pragma unroll
  for (int off = 32; off > 0; off >>= 1) {
    s0 += __shfl_down(s0, off);
    s1 += __shfl_down(s1, off);
    s2 += __shfl_down(s2, off);
    s3 += __shfl_down(s3, off);
  }
  __shared__ float red[4][4];
  const int wv = tid >> 6, ln = tid & 63;
  if (ln == 0) { red[0][wv]=s0; red[1][wv]=s1; red[2][wv]=s2; red[3][wv]=s3; }
  __syncthreads();
  if (tid < 4) {
    float tot = red[tid][0]+red[tid][1]+red[tid][2]+red[tid][3];
    dcsum[2*tid] = tot; dcsum[2*tid+1] = 0.0f;
  }
}

// K2[v][t][cb][2]: weighted k, scaled by 1/(H*W), pair-factor 2 for t in [1,191].
__global__ __launch_bounds__(256) void combine_kernel(
    const float* __restrict__ kpart, const float* __restrict__ dcsum,
    const float* __restrict__ weights, float* __restrict__ K2) {
  const int idx = blockIdx.x*256 + threadIdx.x;
  if (idx >= NVIEWS*HALFT) return;
  const int v = idx / HALFT, t = idx % HALFT;
  float f = weights[t] * (1.0f/36864.0f);   // weights[m] depends only on t
  if (t != 0 && t != 192) f *= 2.0f;
  float o[8];
  if (t == 192) {
    #pragma unroll
    for (int cb = 0; cb < 4; ++cb) { o[2*cb] = f*dcsum[2*cb]; o[2*cb+1] = f*dcsum[2*cb+1]; }
  } else {
    #pragma unroll
    for (int cb = 0; cb < 4; ++cb) {
      float ar = 0.f, ai = 0.f;
      #pragma unroll
      for (int s = 0; s < NSPLIT; ++s) {
        const float* p = kpart + (((s*NVIEWS + v)*192 + t)*4 + cb)*2;
        ar += p[0]; ai += p[1];
      }
      o[2*cb] = f*ar; o[2*cb+1] = f*ai;
    }
  }
  float* q = K2 + idx*8;
  #pragma unroll
  for (int j = 0; j < 8; ++j) q[j] = o[j];
}

// adjoint: img[cb, pix] partial over a 32-view chunk.
// thread = pixel; per view: rotor over t; pairs t in [1,191] are Re-only.
__global__ __launch_bounds__(256) void adj_kernel(
    const float* __restrict__ K2, const float* __restrict__ points,
    float* __restrict__ imgpart) {
  const int pix = blockIdx.x*256 + threadIdx.x;    // 0..36863
  const int chunk = blockIdx.y;
  const float nh = (float)(pix / WW - 96);
  const float nw = (float)(pix % WW - 96);
  float re[4] = {0,0,0,0}, im[4] = {0,0,0,0};
  const float INVPI = 0.3183098861837907f;
  const float PI192 = 3.14159265358979f / 192.0f;
  for (int v = chunk*32; v < chunk*32 + 32; ++v) {
    // recover cos/sin(theta) from the t=0 sample: kx0 = -pi*cos, ky0 = -pi*sin
    const float ct = -points[2*(v*NSAMP)+0] * INVPI;
    const float st = -points[2*(v*NSAMP)+1] * INVPI;
    const float alpha = ct*nh + st*nw;
    const float delta = alpha * PI192;               // per-t phase step
    float dr, di; __sincosf(delta, &di, &dr);
    float cr, ci; __sincosf(-192.0f*delta, &ci, &cr); // phi_0 = -pi*alpha
    const float* Kv = K2 + v*HALFT*8;
    // t = 0: unpaired, full complex
    #pragma unroll
    for (int cb = 0; cb < 4; ++cb) {
      float a = Kv[2*cb], b = Kv[2*cb+1];
      re[cb] += a*cr - b*ci;
      im[cb] += a*ci + b*cr;
    }
    // t = 1..191: conjugate pairs -> 2*Re(K cis) (factor 2 folded into K2)
    for (int t = 1; t < 192; ++t) {
      float nr2 = cr*dr - ci*di;
      float ni2 = cr*di + ci*dr;
      cr = nr2; ci = ni2;
      const float* kt = Kv + t*8;
      #pragma unroll
      for (int cb = 0; cb < 4; ++cb)
        re[cb] += kt[2*cb]*cr - kt[2*cb+1]*ci;
    }
    // t = 192 (DC): cis(0) = 1
    const float* kd = Kv + 192*8;
    #pragma unroll
    for (int cb = 0; cb < 4; ++cb) { re[cb] += kd[2*cb]; im[cb] += kd[2*cb+1]; }
  }
  float* o = imgpart + (chunk*NPIX + pix)*8;
  #pragma unroll
  for (int cb = 0; cb < 4; ++cb) { o[2*cb] = re[cb]; o[2*cb+1] = im[cb]; }
}

__global__ __launch_bounds__(256) void out_kernel(
    const float* __restrict__ imgpart, float* __restrict__ out) {
  const int pix = blockIdx.x*256 + threadIdx.x;
  float re[4] = {0,0,0,0}, im[4] = {0,0,0,0};
  #pragma unroll
  for (int ch = 0; ch < NCHUNK; ++ch) {
    const float* p = imgpart + (ch*NPIX + pix)*8;
    #pragma unroll
    for (int cb = 0; cb < 4; ++cb) { re[cb] += p[2*cb]; im[cb] += p[2*cb+1]; }
  }
  #pragma unroll
  for (int b = 0; b < 2; ++b)
    #pragma unroll
    for (int c = 0; c < 2; ++c) {
      const int cb = b*2 + c;
      out[(b*NPIX + pix)*2 + c] = sqrtf(re[cb]*re[cb] + im[cb]*im[cb]);
    }
}

extern "C" void kernel_launch(void* const* d_in, const int* in_sizes, int n_in,
                              void* d_out, int out_size, void* d_ws, size_t ws_size,
                              hipStream_t stream) {
  const float* x       = (const float*)d_in[0];
  const float* points  = (const float*)d_in[1];
  const float* weights = (const float*)d_in[2];
  float* out = (float*)d_out;
  float* ws  = (float*)d_ws;

  // workspace layout (floats):
  float* kpart   = ws;                 // NSPLIT*128*192*4*2        = 786432
  float* dcsum   = ws + 786432;        // 8
  float* K2      = ws + 786440;        // 128*193*8                 = 197632
  float* imgpart = ws + 984072;        // NCHUNK*36864*8            = 1179648
  // total 2163720 floats = 8.66 MB

  fwd_kernel<<<dim3(NVIEWS, NSPLIT), 192, 0, stream>>>(x, points, kpart);
  dc_kernel<<<1, 256, 0, stream>>>(x, dcsum);
  combine_kernel<<<(NVIEWS*HALFT + 255)/256, 256, 0, stream>>>(kpart, dcsum, weights, K2);
  adj_kernel<<<dim3(NPIX/256, NCHUNK), 256, 0, stream>>>(K2, points, imgpart);
  out_kernel<<<NPIX/256, 256, 0, stream>>>(imgpart, out);
}

// Round 2
// 782.473 us; speedup vs baseline: 1.7098x; 1.7098x over previous
//
#include <hip/hip_runtime.h>
#include <math.h>

// KSpaceResampling: type-2 NUDFT -> ramp weights -> type-1 adjoint -> abs
// Shapes: x [B=2,H=192,W=192,C=2] fp32; points [49152,2]; weights [49152]
// out [2,192,192,2] fp32.
//
// Exact-math reductions:
//  * Hermitian symmetry: x real => k(v, 384-t) = conj(k(v,t)); forward computes
//    t in [0,192] only; adjoint pairs contribute 2*Re(K cis(phi)).
//  * Phase is arithmetic along h, w (forward) and t (adjoint) => complex rotor
//    recurrences instead of per-element sincos.
// Round 1: occupancy fix. adj chunks 4->16 (2304 blocks), fwd splits 4->16
// (2048 blocks); adjoint t-loop unrolled x2 with independent rotor chains.

#define HH 192
#define WW 192
#define NVIEWS 128
#define NSAMP 384
#define NPIX (HH*WW)      // 36864
#define HALFT 193         // stored t = 0..192

__device__ __forceinline__ void rot(float& cr, float& ci, float dr, float di) {
  float nr = cr*dr - ci*di;
  float ni = cr*di + ci*dr;
  cr = nr; ci = ni;
}

// k[cb, v, t] partial over an h-slice of HPER rows.  cb = b*2 + c.
// thread = t (0..191), block = (v, split). t=192 (DC) handled by dc_kernel.
template <int HPER>
__global__ __launch_bounds__(192) void fwd_kernel(
    const float* __restrict__ x, const float* __restrict__ points,
    float* __restrict__ kpart) {
  const int v = blockIdx.x;
  const int split = blockIdx.y;
  const int t = threadIdx.x;                 // 0..191
  const int m = v*NSAMP + t;
  const float kx = points[2*m+0];
  const float ky = points[2*m+1];
  const int h0 = split*HPER;

  float kr[4] = {0,0,0,0}, ki[4] = {0,0,0,0};
  // cis(-ky*(w-96)) state at w=0 and its per-w rotor
  float cyr, cyi; __sincosf(96.0f*ky, &cyi, &cyr);
  float dyr, dyi; __sincosf(-ky, &dyi, &dyr);
  // cis(-kx*(h-96)) start at h=h0 and per-h rotor (constant across wp)
  float cx0r, cx0i; __sincosf(kx*(float)(96-h0), &cx0i, &cx0r);
  float dxr, dxi; __sincosf(-kx, &dxi, &dxr);

  for (int wp = 0; wp < 96; ++wp) {
    const int w0 = wp*2;
    float g0r[4]={0,0,0,0}, g0i[4]={0,0,0,0};   // [cb] at w0
    float g1r[4]={0,0,0,0}, g1i[4]={0,0,0,0};   // [cb] at w0+1
    float cxr = cx0r, cxi = cx0i;
    const float* p0 = x + (h0*WW + w0)*2;            // b=0
    const float* p1 = p0 + HH*WW*2;                  // b=1
    #pragma unroll 4
    for (int h = 0; h < HPER; ++h) {
      // float4 = (w0,c0),(w0,c1),(w1,c0),(w1,c1) — wave-uniform address
      float4 a = *(const float4*)(p0 + h*(WW*2));
      float4 b = *(const float4*)(p1 + h*(WW*2));
      g0r[0] += a.x*cxr; g0i[0] += a.x*cxi;
      g0r[1] += a.y*cxr; g0i[1] += a.y*cxi;
      g1r[0] += a.z*cxr; g1i[0] += a.z*cxi;
      g1r[1] += a.w*cxr; g1i[1] += a.w*cxi;
      g0r[2] += b.x*cxr; g0i[2] += b.x*cxi;
      g0r[3] += b.y*cxr; g0i[3] += b.y*cxi;
      g1r[2] += b.z*cxr; g1i[2] += b.z*cxi;
      g1r[3] += b.w*cxr; g1i[3] += b.w*cxi;
      rot(cxr, cxi, dxr, dxi);
    }
    #pragma unroll
    for (int cb = 0; cb < 4; ++cb) {
      kr[cb] += g0r[cb]*cyr - g0i[cb]*cyi;
      ki[cb] += g0r[cb]*cyi + g0i[cb]*cyr;
    }
    rot(cyr, cyi, dyr, dyi);
    #pragma unroll
    for (int cb = 0; cb < 4; ++cb) {
      kr[cb] += g1r[cb]*cyr - g1i[cb]*cyi;
      ki[cb] += g1r[cb]*cyi + g1i[cb]*cyr;
    }
    rot(cyr, cyi, dyr, dyi);
  }
  float* o = kpart + (((split*NVIEWS + v)*192 + t)*4)*2;
  #pragma unroll
  for (int cb = 0; cb < 4; ++cb) { o[2*cb] = kr[cb]; o[2*cb+1] = ki[cb]; }
}

// DC sample (t=192, r=0): k = sum(x) per cb, exactly real.
__global__ __launch_bounds__(256) void dc_kernel(
    const float* __restrict__ x, float* __restrict__ dcsum) {
  const int tid = threadIdx.x;
  float s0=0.f, s1=0.f, s2=0.f, s3=0.f;
  for (int i = tid; i < NPIX; i += 256) {
    float2 a = *(const float2*)(x + i*2);           // b0: (c0,c1)
    float2 b = *(const float2*)(x + HH*WW*2 + i*2); // b1
    s0 += a.x; s1 += a.y; s2 += b.x; s3 += b.y;
  }
  #pragma unroll
  for (int off = 32; off > 0; off >>= 1) {
    s0 += __shfl_down(s0, off);
    s1 += __shfl_down(s1, off);
    s2 += __shfl_down(s2, off);
    s3 += __shfl_down(s3, off);
  }
  __shared__ float red[4][4];
  const int wv = tid >> 6, ln = tid & 63;
  if (ln == 0) { red[0][wv]=s0; red[1][wv]=s1; red[2][wv]=s2; red[3][wv]=s3; }
  __syncthreads();
  if (tid < 4) {
    float tot = red[tid][0]+red[tid][1]+red[tid][2]+red[tid][3];
    dcsum[2*tid] = tot; dcsum[2*tid+1] = 0.0f;
  }
}

// K2[v][t][cb][2]: weighted k, scaled by 1/(H*W), pair-factor 2 for t in [1,191].
__global__ __launch_bounds__(256) void combine_kernel(
    const float* __restrict__ kpart, const float* __restrict__ dcsum,
    const float* __restrict__ weights, float* __restrict__ K2, int nsplit) {
  const int idx = blockIdx.x*256 + threadIdx.x;
  if (idx >= NVIEWS*HALFT) return;
  const int v = idx / HALFT, t = idx % HALFT;
  float f = weights[t] * (1.0f/36864.0f);   // weights[m] depends only on t
  if (t != 0 && t != 192) f *= 2.0f;
  float o[8];
  if (t == 192) {
    #pragma unroll
    for (int cb = 0; cb < 4; ++cb) { o[2*cb] = f*dcsum[2*cb]; o[2*cb+1] = f*dcsum[2*cb+1]; }
  } else {
    #pragma unroll
    for (int cb = 0; cb < 4; ++cb) {
      float ar = 0.f, ai = 0.f;
      for (int s = 0; s < nsplit; ++s) {
        const float* p = kpart + (((s*NVIEWS + v)*192 + t)*4 + cb)*2;
        ar += p[0]; ai += p[1];
      }
      o[2*cb] = f*ar; o[2*cb+1] = f*ai;
    }
  }
  float* q = K2 + idx*8;
  #pragma unroll
  for (int j = 0; j < 8; ++j) q[j] = o[j];
}

// adjoint: img[cb, pix] partial over a VPC-view chunk.
// thread = pixel; per view: two independent rotor chains (even/odd t),
// paired t in [1,191] are Re-only.
template <int VPC>
__global__ __launch_bounds__(256) void adj_kernel(
    const float* __restrict__ K2, const float* __restrict__ points,
    float* __restrict__ imgpart) {
  const int pix = blockIdx.x*256 + threadIdx.x;    // 0..36863
  const int chunk = blockIdx.y;
  const float nh = (float)(pix / WW - 96);
  const float nw = (float)(pix % WW - 96);
  float re[4] = {0,0,0,0}, im[4] = {0,0,0,0};
  const float INVPI = 0.3183098861837907f;
  const float PI192 = 3.14159265358979f / 192.0f;
  for (int v = chunk*VPC; v < chunk*VPC + VPC; ++v) {
    // recover cos/sin(theta) from the t=0 sample: kx0 = -pi*cos, ky0 = -pi*sin
    const float ct = -points[2*(v*NSAMP)+0] * INVPI;
    const float st = -points[2*(v*NSAMP)+1] * INVPI;
    const float alpha = ct*nh + st*nw;
    const float delta = alpha * PI192;               // per-t phase step
    float dr, di; __sincosf(delta, &di, &dr);
    float c0r, c0i; __sincosf(-192.0f*delta, &c0i, &c0r); // phi_0 = -pi*alpha
    const float* Kv = K2 + v*HALFT*8;
    // t = 0: unpaired, full complex
    #pragma unroll
    for (int cb = 0; cb < 4; ++cb) {
      float a = Kv[2*cb], b = Kv[2*cb+1];
      re[cb] += a*c0r - b*c0i;
      im[cb] += a*c0i + b*c0r;
    }
    // two chains: A covers t=1,3,..,191; B covers t=2,4,..,190; step cis(2*delta)
    float d2r = dr*dr - di*di, d2i = 2.0f*dr*di;
    float ar = c0r*dr - c0i*di, ai = c0r*di + c0i*dr;  // cis(phi_0 + delta)
    float br = ar*dr - ai*di,  bi = ar*di + ai*dr;     // cis(phi_0 + 2delta)
    for (int i = 0; i < 95; ++i) {
      const float* ka = Kv + (2*i+1)*8;
      const float* kb = Kv + (2*i+2)*8;
      #pragma unroll
      for (int cb = 0; cb < 4; ++cb)
        re[cb] += ka[2*cb]*ar - ka[2*cb+1]*ai;
      #pragma unroll
      for (int cb = 0; cb < 4; ++cb)
        re[cb] += kb[2*cb]*br - kb[2*cb+1]*bi;
      rot(ar, ai, d2r, d2i);
      rot(br, bi, d2r, d2i);
    }
    // t = 191 with chain A
    {
      const float* ka = Kv + 191*8;
      #pragma unroll
      for (int cb = 0; cb < 4; ++cb)
        re[cb] += ka[2*cb]*ar - ka[2*cb+1]*ai;
    }
    // t = 192 (DC): cis(0) = 1
    const float* kd = Kv + 192*8;
    #pragma unroll
    for (int cb = 0; cb < 4; ++cb) { re[cb] += kd[2*cb]; im[cb] += kd[2*cb+1]; }
  }
  float* o = imgpart + (chunk*NPIX + pix)*8;
  #pragma unroll
  for (int cb = 0; cb < 4; ++cb) { o[2*cb] = re[cb]; o[2*cb+1] = im[cb]; }
}

__global__ __launch_bounds__(256) void out_kernel(
    const float* __restrict__ imgpart, float* __restrict__ out, int nchunk) {
  const int pix = blockIdx.x*256 + threadIdx.x;
  float re[4] = {0,0,0,0}, im[4] = {0,0,0,0};
  for (int ch = 0; ch < nchunk; ++ch) {
    const float* p = imgpart + (ch*NPIX + pix)*8;
    #pragma unroll
    for (int cb = 0; cb < 4; ++cb) { re[cb] += p[2*cb]; im[cb] += p[2*cb+1]; }
  }
  #pragma unroll
  for (int b = 0; b < 2; ++b)
    #pragma unroll
    for (int c = 0; c < 2; ++c) {
      const int cb = b*2 + c;
      out[(b*NPIX + pix)*2 + c] = sqrtf(re[cb]*re[cb] + im[cb]*im[cb]);
    }
}

extern "C" void kernel_launch(void* const* d_in, const int* in_sizes, int n_in,
                              void* d_out, int out_size, void* d_ws, size_t ws_size,
                              hipStream_t stream) {
  const float* x       = (const float*)d_in[0];
  const float* points  = (const float*)d_in[1];
  const float* weights = (const float*)d_in[2];
  float* out = (float*)d_out;
  float* ws  = (float*)d_ws;

  // pick largest nsplit/nchunk that fit the workspace
  const size_t ws_floats = ws_size / sizeof(float);
  int nsplit = 16, nchunk = 16;
  auto need = [&](int ns, int nc) -> size_t {
    return (size_t)ns*196608 + 8 + 197632 + (size_t)nc*294912;
  };
  while (need(nsplit, nchunk) > ws_floats && nchunk > 1) nchunk >>= 1;
  while (need(nsplit, nchunk) > ws_floats && nsplit > 1) nsplit >>= 1;

  float* kpart   = ws;                                   // nsplit*128*192*4*2
  float* dcsum   = kpart + (size_t)nsplit*196608;        // 8
  float* K2      = dcsum + 8;                            // 128*193*8 = 197632
  float* imgpart = K2 + 197632;                          // nchunk*36864*8

  switch (nsplit) {
    case 16: fwd_kernel<12><<<dim3(NVIEWS,16), 192, 0, stream>>>(x, points, kpart); break;
    case 8:  fwd_kernel<24><<<dim3(NVIEWS,8),  192, 0, stream>>>(x, points, kpart); break;
    case 4:  fwd_kernel<48><<<dim3(NVIEWS,4),  192, 0, stream>>>(x, points, kpart); break;
    case 2:  fwd_kernel<96><<<dim3(NVIEWS,2),  192, 0, stream>>>(x, points, kpart); break;
    default: fwd_kernel<192><<<dim3(NVIEWS,1), 192, 0, stream>>>(x, points, kpart); break;
  }
  dc_kernel<<<1, 256, 0, stream>>>(x, dcsum);
  combine_kernel<<<(NVIEWS*HALFT + 255)/256, 256, 0, stream>>>(kpart, dcsum, weights, K2, nsplit);
  switch (nchunk) {
    case 16: adj_kernel<8>  <<<dim3(NPIX/256,16), 256, 0, stream>>>(K2, points, imgpart); break;
    case 8:  adj_kernel<16> <<<dim3(NPIX/256,8),  256, 0, stream>>>(K2, points, imgpart); break;
    case 4:  adj_kernel<32> <<<dim3(NPIX/256,4),  256, 0, stream>>>(K2, points, imgpart); break;
    case 2:  adj_kernel<64> <<<dim3(NPIX/256,2),  256, 0, stream>>>(K2, points, imgpart); break;
    default: adj_kernel<128><<<dim3(NPIX/256,1),  256, 0, stream>>>(K2, points, imgpart); break;
  }
  out_kernel<<<NPIX/256, 256, 0, stream>>>(imgpart, out, nchunk);
}

// Round 3
// 476.167 us; speedup vs baseline: 2.8096x; 1.6433x over previous
//
#include <hip/hip_runtime.h>
#include <math.h>

// KSpaceResampling: type-2 NUDFT -> ramp weights -> type-1 adjoint -> abs
// R3: adjoint as bf16 MFMA GEMM (factorized phases + v-pairing + t-Hermitian),
// forward stays the r2 rotor kernel. Fallback to full r2 path if ws too small.

#define HH 192
#define WW 192
#define NVIEWS 128
#define NSAMP 384
#define NPIX (HH*WW)      // 36864
#define HALFT 193         // stored t = 0..192
#define M2 12545          // 65 * 193  (v2 in [0,64])
#define M2P 12672         // padded
#define KTOT 25344        // 2 * M2P   (Cy-part ; Sy-part)
#define NSPLITK 33        // adjoint GEMM K-split (25344/33 = 768 = 24*32)

typedef __attribute__((ext_vector_type(8))) short bf16x8;
typedef __attribute__((ext_vector_type(4))) float f32x4;

__device__ __forceinline__ void rot(float& cr, float& ci, float dr, float di) {
  float nr = cr*dr - ci*di;
  float ni = cr*di + ci*dr;
  cr = nr; ci = ni;
}
__device__ __forceinline__ unsigned short f2b(float f) {
  unsigned int u = __float_as_uint(f);
  u += 0x7fffu + ((u >> 16) & 1u);
  return (unsigned short)(u >> 16);
}
__device__ __forceinline__ float b2f(unsigned short h) {
  return __uint_as_float(((unsigned int)h) << 16);
}

// ---------------- forward (r2, validated) ----------------

template <int HPER>
__global__ __launch_bounds__(192) void fwd_kernel(
    const float* __restrict__ x, const float* __restrict__ points,
    float* __restrict__ kpart) {
  const int v = blockIdx.x;
  const int split = blockIdx.y;
  const int t = threadIdx.x;                 // 0..191
  const int m = v*NSAMP + t;
  const float kx = points[2*m+0];
  const float ky = points[2*m+1];
  const int h0 = split*HPER;

  float kr[4] = {0,0,0,0}, ki[4] = {0,0,0,0};
  float cyr, cyi; __sincosf(96.0f*ky, &cyi, &cyr);
  float dyr, dyi; __sincosf(-ky, &dyi, &dyr);
  float cx0r, cx0i; __sincosf(kx*(float)(96-h0), &cx0i, &cx0r);
  float dxr, dxi; __sincosf(-kx, &dxi, &dxr);

  for (int wp = 0; wp < 96; ++wp) {
    const int w0 = wp*2;
    float g0r[4]={0,0,0,0}, g0i[4]={0,0,0,0};
    float g1r[4]={0,0,0,0}, g1i[4]={0,0,0,0};
    float cxr = cx0r, cxi = cx0i;
    const float* p0 = x + (h0*WW + w0)*2;
    const float* p1 = p0 + HH*WW*2;
    #pragma unroll 4
    for (int h = 0; h < HPER; ++h) {
      float4 a = *(const float4*)(p0 + h*(WW*2));
      float4 b = *(const float4*)(p1 + h*(WW*2));
      g0r[0] += a.x*cxr; g0i[0] += a.x*cxi;
      g0r[1] += a.y*cxr; g0i[1] += a.y*cxi;
      g1r[0] += a.z*cxr; g1i[0] += a.z*cxi;
      g1r[1] += a.w*cxr; g1i[1] += a.w*cxi;
      g0r[2] += b.x*cxr; g0i[2] += b.x*cxi;
      g0r[3] += b.y*cxr; g0i[3] += b.y*cxi;
      g1r[2] += b.z*cxr; g1i[2] += b.z*cxi;
      g1r[3] += b.w*cxr; g1i[3] += b.w*cxi;
      rot(cxr, cxi, dxr, dxi);
    }
    #pragma unroll
    for (int cb = 0; cb < 4; ++cb) {
      kr[cb] += g0r[cb]*cyr - g0i[cb]*cyi;
      ki[cb] += g0r[cb]*cyi + g0i[cb]*cyr;
    }
    rot(cyr, cyi, dyr, dyi);
    #pragma unroll
    for (int cb = 0; cb < 4; ++cb) {
      kr[cb] += g1r[cb]*cyr - g1i[cb]*cyi;
      ki[cb] += g1r[cb]*cyi + g1i[cb]*cyr;
    }
    rot(cyr, cyi, dyr, dyi);
  }
  float* o = kpart + (((split*NVIEWS + v)*192 + t)*4)*2;
  #pragma unroll
  for (int cb = 0; cb < 4; ++cb) { o[2*cb] = kr[cb]; o[2*cb+1] = ki[cb]; }
}

__global__ __launch_bounds__(256) void dc_kernel(
    const float* __restrict__ x, float* __restrict__ dcsum) {
  const int tid = threadIdx.x;
  float s0=0.f, s1=0.f, s2=0.f, s3=0.f;
  for (int i = tid; i < NPIX; i += 256) {
    float2 a = *(const float2*)(x + i*2);
    float2 b = *(const float2*)(x + HH*WW*2 + i*2);
    s0 += a.x; s1 += a.y; s2 += b.x; s3 += b.y;
  }
  #pragma unroll
  for (int off = 32; off > 0; off >>= 1) {
    s0 += __shfl_down(s0, off);
    s1 += __shfl_down(s1, off);
    s2 += __shfl_down(s2, off);
    s3 += __shfl_down(s3, off);
  }
  __shared__ float red[4][4];
  const int wv = tid >> 6, ln = tid & 63;
  if (ln == 0) { red[0][wv]=s0; red[1][wv]=s1; red[2][wv]=s2; red[3][wv]=s3; }
  __syncthreads();
  if (tid < 4) {
    float tot = red[tid][0]+red[tid][1]+red[tid][2]+red[tid][3];
    dcsum[2*tid] = tot; dcsum[2*tid+1] = 0.0f;
  }
}

// K2[idx=(v,t)][cb][2]: weighted k, 1/(H*W) and pair-factor-2 folded in.
__global__ __launch_bounds__(256) void combine_kernel(
    const float* __restrict__ kpart, const float* __restrict__ dcsum,
    const float* __restrict__ weights, float* __restrict__ K2, int nsplit) {
  const int idx = blockIdx.x*256 + threadIdx.x;
  if (idx >= NVIEWS*HALFT) return;
  const int v = idx / HALFT, t = idx % HALFT;
  float f = weights[t] * (1.0f/36864.0f);
  if (t != 0 && t != 192) f *= 2.0f;
  float o[8];
  if (t == 192) {
    #pragma unroll
    for (int cb = 0; cb < 4; ++cb) { o[2*cb] = f*dcsum[2*cb]; o[2*cb+1] = f*dcsum[2*cb+1]; }
  } else {
    #pragma unroll
    for (int cb = 0; cb < 4; ++cb) {
      float ar = 0.f, ai = 0.f;
      for (int s = 0; s < nsplit; ++s) {
        const float* p = kpart + (((s*NVIEWS + v)*192 + t)*4 + cb)*2;
        ar += p[0]; ai += p[1];
      }
      o[2*cb] = f*ar; o[2*cb+1] = f*ai;
    }
  }
  float* q = K2 + idx*8;
  #pragma unroll
  for (int j = 0; j < 8; ++j) q[j] = o[j];
}

// ---------------- adjoint, MFMA path ----------------

// BT[w][KTOT]: cols [0,M2) = cos(ky*nw), cols [M2P, M2P+M2) = sin(ky*nw)
__global__ __launch_bounds__(256) void ygen_kernel(
    const float* __restrict__ points, unsigned short* __restrict__ BT) {
  const int v2 = blockIdx.x;
  const int t = threadIdx.x;
  if (t >= HALFT) return;
  const float ky = points[(v2*NSAMP + t)*2 + 1];
  const int kap = v2*HALFT + t;
  float cr, ci; __sincosf(-96.0f*ky, &ci, &cr);
  float dr, di; __sincosf(ky, &di, &dr);
  for (int w = 0; w < 192; ++w) {
    BT[(size_t)w*KTOT + kap]       = f2b(cr);
    BT[(size_t)w*KTOT + M2P + kap] = f2b(ci);
    rot(cr, ci, dr, di);
  }
}

// CxT[h][M2P] = cos(kx*nh), SxT[h][M2P] = sin(kx*nh)
__global__ __launch_bounds__(256) void xgen_kernel(
    const float* __restrict__ points, unsigned short* __restrict__ CxT,
    unsigned short* __restrict__ SxT) {
  const int v2 = blockIdx.x;
  const int t = threadIdx.x;
  if (t >= HALFT) return;
  const float kx = points[(v2*NSAMP + t)*2 + 0];
  const int kap = v2*HALFT + t;
  float cr, ci; __sincosf(-96.0f*kx, &ci, &cr);
  float dr, di; __sincosf(kx, &di, &dr);
  for (int h = 0; h < 192; ++h) {
    CxT[(size_t)h*M2P + kap] = f2b(cr);
    SxT[(size_t)h*M2P + kap] = f2b(ci);
    rot(cr, ci, dr, di);
  }
}

// combos[cb][q][M2P], q: 0=KrS 1=KrD 2=KiS 3=KiD  (v paired with 128-v)
__global__ __launch_bounds__(256) void combo_kernel(
    const float* __restrict__ K2, float* __restrict__ combos) {
  const int m2 = blockIdx.x*256 + threadIdx.x;
  if (m2 >= M2) return;
  const int v2 = m2 / HALFT, t = m2 - v2*HALFT;
  const bool hp = (v2 >= 1 && v2 <= 63);
  const int mp = (128 - v2)*HALFT + t;
  #pragma unroll
  for (int cb = 0; cb < 4; ++cb) {
    float kr = K2[m2*8 + cb*2], ki = K2[m2*8 + cb*2 + 1];
    float krp = hp ? K2[mp*8 + cb*2] : 0.f;
    float kip = hp ? K2[mp*8 + cb*2 + 1] : 0.f;
    combos[(cb*4+0)*M2P + m2] = kr + krp;
    combos[(cb*4+1)*M2P + m2] = kr - krp;
    combos[(cb*4+2)*M2P + m2] = ki + kip;
    combos[(cb*4+3)*M2P + m2] = ki - kip;
  }
}

// A[j=(cb,h)][KTOT]: cols [0,M2P) = P, cols [M2P,KTOT) = Q
//   P = KrS*Cx - KiD*Sx ; Q = -(KrD*Sx + KiS*Cx)
__global__ __launch_bounds__(256) void tmat_kernel(
    const float* __restrict__ combos, const unsigned short* __restrict__ CxT,
    const unsigned short* __restrict__ SxT, unsigned short* __restrict__ A) {
  const int m2 = blockIdx.x*256 + threadIdx.x;
  if (m2 >= M2P) return;
  const int j = blockIdx.y;
  unsigned short* Arow = A + (size_t)j*KTOT;
  if (m2 >= M2) { Arow[m2] = 0; Arow[M2P + m2] = 0; return; }
  const int cb = j / 192, h = j - cb*192;
  const float cx = b2f(CxT[(size_t)h*M2P + m2]);
  const float sx = b2f(SxT[(size_t)h*M2P + m2]);
  const float c0 = combos[(cb*4+0)*M2P + m2];
  const float c1 = combos[(cb*4+1)*M2P + m2];
  const float c2 = combos[(cb*4+2)*M2P + m2];
  const float c3 = combos[(cb*4+3)*M2P + m2];
  Arow[m2]       = f2b(c0*cx - c3*sx);
  Arow[M2P + m2] = f2b(-(c1*sx + c2*cx));
}

// partials[kc][w][j] += A[j][.]*BT[w][.] over K-chunk kc. Barrier-free GEMM,
// fragments direct from global (L2/L3-resident operands).
__global__ __launch_bounds__(256) void adj_gemm(
    const unsigned short* __restrict__ A, const unsigned short* __restrict__ BT,
    float* __restrict__ partials) {
  const int mt = blockIdx.x;   // 0..5   (128 j-rows)
  const int kc = blockIdx.y;   // 0..32  (768 K each)
  const int wv = threadIdx.x >> 6;
  const int lane = threadIdx.x & 63;
  const int r = lane & 15, kg = lane >> 4;
  const int jbase = mt*128 + (wv>>1)*64;
  const int wbase = (wv&1)*96;
  const int kb = kc*768 + kg*8;

  f32x4 acc[4][6];
  #pragma unroll
  for (int a = 0; a < 4; ++a)
    #pragma unroll
    for (int b = 0; b < 6; ++b) acc[a][b] = (f32x4){0.f,0.f,0.f,0.f};

  const unsigned short* Ap = A + (size_t)(jbase + r)*KTOT + kb;
  const unsigned short* Bp = BT + (size_t)(wbase + r)*KTOT + kb;
  for (int ks = 0; ks < 24; ++ks) {
    bf16x8 af[4], bfr[6];
    #pragma unroll
    for (int mf = 0; mf < 4; ++mf)
      af[mf] = *(const bf16x8*)(Ap + (size_t)mf*16*KTOT + ks*32);
    #pragma unroll
    for (int nf = 0; nf < 6; ++nf)
      bfr[nf] = *(const bf16x8*)(Bp + (size_t)nf*16*KTOT + ks*32);
    #pragma unroll
    for (int mf = 0; mf < 4; ++mf)
      #pragma unroll
      for (int nf = 0; nf < 6; ++nf)
        acc[mf][nf] = __builtin_amdgcn_mfma_f32_16x16x32_bf16(
            af[mf], bfr[nf], acc[mf][nf], 0, 0, 0);
  }
  float* base = partials + (size_t)kc*192*768;
  #pragma unroll
  for (int mf = 0; mf < 4; ++mf)
    #pragma unroll
    for (int nf = 0; nf < 6; ++nf) {
      const int w = wbase + nf*16 + r;            // C/D col = lane&15
      const int j = jbase + mf*16 + kg*4;         // C/D row = (lane>>4)*4+reg
      *(f32x4*)(base + (size_t)w*768 + j) = acc[mf][nf];
    }
}

// imag part: only unpaired samples (t in {0,192}, all 128 views)
__global__ __launch_bounds__(256) void im_kernel(
    const unsigned short* __restrict__ BT, const unsigned short* __restrict__ CxT,
    const unsigned short* __restrict__ SxT, const float* __restrict__ K2,
    float* __restrict__ imb) {
  __shared__ float cxs[130][16], sxs[130][16], cys[130][16], sys[130][16];
  const int bx = blockIdx.x;            // 144 = 12x12 tiles of 16x16 pixels
  const int h0 = (bx/12)*16, w0 = (bx%12)*16;
  const int tid = threadIdx.x;
  for (int i = tid; i < 130*16; i += 256) {
    const int s = i >> 4, e = i & 15;
    const int v2 = s >> 1, tt = (s & 1)*192;
    const int kap = v2*HALFT + tt;
    cxs[s][e] = b2f(CxT[(size_t)(h0+e)*M2P + kap]);
    sxs[s][e] = b2f(SxT[(size_t)(h0+e)*M2P + kap]);
    cys[s][e] = b2f(BT[(size_t)(w0+e)*KTOT + kap]);
    sys[s][e] = b2f(BT[(size_t)(w0+e)*KTOT + M2P + kap]);
  }
  __syncthreads();
  const int hi = tid >> 4, wi = tid & 15;
  float im[4] = {0,0,0,0};
  for (int v = 0; v < 128; ++v) {
    const int v2 = (v <= 64) ? v : 128 - v;
    const float sg = (v <= 64) ? 1.f : -1.f;
    #pragma unroll
    for (int d = 0; d < 2; ++d) {
      const int s = v2*2 + d;
      const float cx = cxs[s][hi], sx = sg*sxs[s][hi];
      const float cy = cys[s][wi], sy = sys[s][wi];
      const float t1 = cx*sy + sx*cy;   // Im phase coeff of Kr
      const float t2 = cx*cy - sx*sy;   // Im phase coeff of Ki
      const int idx = (v*HALFT + d*192)*8;
      #pragma unroll
      for (int cb = 0; cb < 4; ++cb)
        im[cb] += K2[idx + cb*2]*t1 + K2[idx + cb*2 + 1]*t2;
    }
  }
  const int pix = (h0+hi)*192 + (w0+wi);
  *(float4*)(imb + pix*4) = make_float4(im[0], im[1], im[2], im[3]);
}

__global__ __launch_bounds__(256) void out_new_kernel(
    const float* __restrict__ partials, const float* __restrict__ imb,
    float* __restrict__ out) {
  const int g = blockIdx.x*256 + threadIdx.x;    // < 192*768
  const int w = g / 768, cbh = g - w*768;
  const int cb = cbh / 192, h = cbh - cb*192;
  float re = 0.f;
  for (int kc = 0; kc < NSPLITK; ++kc)
    re += partials[(size_t)kc*147456 + g];
  const float im = imb[(h*192 + w)*4 + cb];
  const float mag = sqrtf(re*re + im*im);
  const int b = cb >> 1, c = cb & 1;
  out[((size_t)b*NPIX + h*192 + w)*2 + c] = mag;
}

// ---------------- fallback (r2 adjoint) ----------------

template <int VPC>
__global__ __launch_bounds__(256) void adj_kernel(
    const float* __restrict__ K2, const float* __restrict__ points,
    float* __restrict__ imgpart) {
  const int pix = blockIdx.x*256 + threadIdx.x;
  const int chunk = blockIdx.y;
  const float nh = (float)(pix / WW - 96);
  const float nw = (float)(pix % WW - 96);
  float re[4] = {0,0,0,0}, im[4] = {0,0,0,0};
  const float INVPI = 0.3183098861837907f;
  const float PI192 = 3.14159265358979f / 192.0f;
  for (int v = chunk*VPC; v < chunk*VPC + VPC; ++v) {
    const float ct = -points[2*(v*NSAMP)+0] * INVPI;
    const float st = -points[2*(v*NSAMP)+1] * INVPI;
    const float alpha = ct*nh + st*nw;
    const float delta = alpha * PI192;
    float dr, di; __sincosf(delta, &di, &dr);
    float c0r, c0i; __sincosf(-192.0f*delta, &c0i, &c0r);
    const float* Kv = K2 + v*HALFT*8;
    #pragma unroll
    for (int cb = 0; cb < 4; ++cb) {
      float a = Kv[2*cb], b = Kv[2*cb+1];
      re[cb] += a*c0r - b*c0i;
      im[cb] += a*c0i + b*c0r;
    }
    float d2r = dr*dr - di*di, d2i = 2.0f*dr*di;
    float ar = c0r*dr - c0i*di, ai = c0r*di + c0i*dr;
    float br = ar*dr - ai*di,  bi = ar*di + ai*dr;
    for (int i = 0; i < 95; ++i) {
      const float* ka = Kv + (2*i+1)*8;
      const float* kb = Kv + (2*i+2)*8;
      #pragma unroll
      for (int cb = 0; cb < 4; ++cb)
        re[cb] += ka[2*cb]*ar - ka[2*cb+1]*ai;
      #pragma unroll
      for (int cb = 0; cb < 4; ++cb)
        re[cb] += kb[2*cb]*br - kb[2*cb+1]*bi;
      rot(ar, ai, d2r, d2i);
      rot(br, bi, d2r, d2i);
    }
    {
      const float* ka = Kv + 191*8;
      #pragma unroll
      for (int cb = 0; cb < 4; ++cb)
        re[cb] += ka[2*cb]*ar - ka[2*cb+1]*ai;
    }
    const float* kd = Kv + 192*8;
    #pragma unroll
    for (int cb = 0; cb < 4; ++cb) { re[cb] += kd[2*cb]; im[cb] += kd[2*cb+1]; }
  }
  float* o = imgpart + (chunk*NPIX + pix)*8;
  #pragma unroll
  for (int cb = 0; cb < 4; ++cb) { o[2*cb] = re[cb]; o[2*cb+1] = im[cb]; }
}

__global__ __launch_bounds__(256) void out_fb_kernel(
    const float* __restrict__ imgpart, float* __restrict__ out, int nchunk) {
  const int pix = blockIdx.x*256 + threadIdx.x;
  float re[4] = {0,0,0,0}, im[4] = {0,0,0,0};
  for (int ch = 0; ch < nchunk; ++ch) {
    const float* p = imgpart + (ch*NPIX + pix)*8;
    #pragma unroll
    for (int cb = 0; cb < 4; ++cb) { re[cb] += p[2*cb]; im[cb] += p[2*cb+1]; }
  }
  #pragma unroll
  for (int b = 0; b < 2; ++b)
    #pragma unroll
    for (int c = 0; c < 2; ++c) {
      const int cb = b*2 + c;
      out[(b*NPIX + pix)*2 + c] = sqrtf(re[cb]*re[cb] + im[cb]*im[cb]);
    }
}

extern "C" void kernel_launch(void* const* d_in, const int* in_sizes, int n_in,
                              void* d_out, int out_size, void* d_ws, size_t ws_size,
                              hipStream_t stream) {
  const float* x       = (const float*)d_in[0];
  const float* points  = (const float*)d_in[1];
  const float* weights = (const float*)d_in[2];
  float* out = (float*)d_out;

  const size_t NEED = 80048384ull;
  if (ws_size >= NEED) {
    char* wsb = (char*)d_ws;
    unsigned short* BT   = (unsigned short*)(wsb + 0);          //  9,732,096 B
    unsigned short* CxT  = (unsigned short*)(wsb + 9732096);    //  4,866,048
    unsigned short* SxT  = (unsigned short*)(wsb + 14598144);   //  4,866,048
    float* K2            = (float*)(wsb + 19464192);            //    790,528
    float* combos        = (float*)(wsb + 20254720);            //    811,008
    float* dcsum         = (float*)(wsb + 21065728);            //        256
    float* kpart         = (float*)(wsb + 21065984);            // 12.6M (dies)
    unsigned short* Aadj = (unsigned short*)(wsb + 21065984);   // 38.9M (reuse)
    float* partials      = (float*)(wsb + 59994368);            // 19,464,192
    float* imb           = (float*)(wsb + 79458560);            //    589,824

    ygen_kernel<<<65, 256, 0, stream>>>(points, BT);
    xgen_kernel<<<65, 256, 0, stream>>>(points, CxT, SxT);
    fwd_kernel<12><<<dim3(NVIEWS,16), 192, 0, stream>>>(x, points, kpart);
    dc_kernel<<<1, 256, 0, stream>>>(x, dcsum);
    combine_kernel<<<(NVIEWS*HALFT + 255)/256, 256, 0, stream>>>(
        kpart, dcsum, weights, K2, 16);
    combo_kernel<<<(M2 + 255)/256, 256, 0, stream>>>(K2, combos);
    tmat_kernel<<<dim3((M2P + 255)/256, 768), 256, 0, stream>>>(
        combos, CxT, SxT, Aadj);
    adj_gemm<<<dim3(6, NSPLITK), 256, 0, stream>>>(Aadj, BT, partials);
    im_kernel<<<144, 256, 0, stream>>>(BT, CxT, SxT, K2, imb);
    out_new_kernel<<<(192*768)/256, 256, 0, stream>>>(partials, imb, out);
  } else {
    // r2 fallback path
    float* ws = (float*)d_ws;
    const size_t ws_floats = ws_size / sizeof(float);
    int nsplit = 16, nchunk = 16;
    auto need = [&](int ns, int nc) -> size_t {
      return (size_t)ns*196608 + 8 + 197632 + (size_t)nc*294912;
    };
    while (need(nsplit, nchunk) > ws_floats && nchunk > 1) nchunk >>= 1;
    while (need(nsplit, nchunk) > ws_floats && nsplit > 1) nsplit >>= 1;

    float* kpart   = ws;
    float* dcsum   = kpart + (size_t)nsplit*196608;
    float* K2      = dcsum + 8;
    float* imgpart = K2 + 197632;

    switch (nsplit) {
      case 16: fwd_kernel<12><<<dim3(NVIEWS,16), 192, 0, stream>>>(x, points, kpart); break;
      case 8:  fwd_kernel<24><<<dim3(NVIEWS,8),  192, 0, stream>>>(x, points, kpart); break;
      case 4:  fwd_kernel<48><<<dim3(NVIEWS,4),  192, 0, stream>>>(x, points, kpart); break;
      case 2:  fwd_kernel<96><<<dim3(NVIEWS,2),  192, 0, stream>>>(x, points, kpart); break;
      default: fwd_kernel<192><<<dim3(NVIEWS,1), 192, 0, stream>>>(x, points, kpart); break;
    }
    dc_kernel<<<1, 256, 0, stream>>>(x, dcsum);
    combine_kernel<<<(NVIEWS*HALFT + 255)/256, 256, 0, stream>>>(
        kpart, dcsum, weights, K2, nsplit);
    switch (nchunk) {
      case 16: adj_kernel<8>  <<<dim3(NPIX/256,16), 256, 0, stream>>>(K2, points, imgpart); break;
      case 8:  adj_kernel<16> <<<dim3(NPIX/256,8),  256, 0, stream>>>(K2, points, imgpart); break;
      case 4:  adj_kernel<32> <<<dim3(NPIX/256,4),  256, 0, stream>>>(K2, points, imgpart); break;
      case 2:  adj_kernel<64> <<<dim3(NPIX/256,2),  256, 0, stream>>>(K2, points, imgpart); break;
      default: adj_kernel<128><<<dim3(NPIX/256,1),  256, 0, stream>>>(K2, points, imgpart); break;
    }
    out_fb_kernel<<<NPIX/256, 256, 0, stream>>>(imgpart, out, nchunk);
  }
}

// Round 4
// 202.829 us; speedup vs baseline: 6.5960x; 2.3476x over previous
//
#include <hip/hip_runtime.h>
#include <math.h>

// KSpaceResampling: type-2 NUDFT -> ramp weights -> type-1 adjoint -> abs
// R4: BOTH directions via bf16 MFMA GEMM.
//  forward:  gemm1 (phases x X over h) -> stage2 (rotor contract over w,
//            emits adjoint combos + K2edge directly)
//  adjoint:  tmat -> adj_gemm -> im -> out   (validated in R3)
// Fallback to the r2 rotor path if ws too small.

#define HH 192
#define WW 192
#define NVIEWS 128
#define NSAMP 384
#define NPIX (HH*WW)      // 36864
#define HALFT 193         // stored t = 0..192
#define M2 12545          // 65 * 193  (v2 in [0,64])
#define M2P 12672         // padded
#define KTOT 25344        // 2 * M2P   (adjoint GEMM K: Cy-part ; Sy-part)
#define NSPLITK 33        // adjoint GEMM K-split (25344/33 = 768)

typedef __attribute__((ext_vector_type(8))) short bf16x8;
typedef __attribute__((ext_vector_type(4))) float f32x4;
typedef __attribute__((ext_vector_type(8))) unsigned short u16x8;

__device__ __forceinline__ void rot(float& cr, float& ci, float dr, float di) {
  float nr = cr*dr - ci*di;
  float ni = cr*di + ci*dr;
  cr = nr; ci = ni;
}
__device__ __forceinline__ unsigned short f2b(float f) {
  unsigned int u = __float_as_uint(f);
  u += 0x7fffu + ((u >> 16) & 1u);
  return (unsigned short)(u >> 16);
}
__device__ __forceinline__ float b2f(unsigned short h) {
  return __uint_as_float(((unsigned int)h) << 16);
}

// ---------------- phase tables ----------------

// BT[w][KTOT]: cols [0,M2) = cos(ky*nw), cols [M2P,M2P+M2) = sin(ky*nw)
__global__ __launch_bounds__(256) void ygen_kernel(
    const float* __restrict__ points, unsigned short* __restrict__ BT) {
  const int v2 = blockIdx.x;
  const int wsplit = blockIdx.y;       // 0..3
  const int t = threadIdx.x;
  if (t >= HALFT) return;
  const float ky = points[(v2*NSAMP + t)*2 + 1];
  const int kap = v2*HALFT + t;
  const int w0 = wsplit*48;
  float cr, ci; __sincosf(ky*(float)(w0-96), &ci, &cr);
  float dr, di; __sincosf(ky, &di, &dr);
  for (int j = 0; j < 48; ++j) {
    BT[(size_t)(w0+j)*KTOT + kap]       = f2b(cr);
    BT[(size_t)(w0+j)*KTOT + M2P + kap] = f2b(ci);
    rot(cr, ci, dr, di);
  }
}

// CxT[h][M2P]=cos(kx*nh), SxT[h][M2P]=sin(kx*nh)  (h-major, for tmat/im)
// Am[m][192]: rows [0,12672) = Cx, rows [12672,25344) = Sx (m2-major, gemm1 A)
__global__ __launch_bounds__(256) void xgen_kernel(
    const float* __restrict__ points, unsigned short* __restrict__ CxT,
    unsigned short* __restrict__ SxT, unsigned short* __restrict__ Am) {
  const int v2 = blockIdx.x;
  const int hsplit = blockIdx.y;       // 0..3
  const int t = threadIdx.x;
  if (t >= HALFT) return;
  const float kx = points[(v2*NSAMP + t)*2 + 0];
  const int m2 = v2*HALFT + t;
  const int h0 = hsplit*48;
  float cr, ci; __sincosf(kx*(float)(h0-96), &ci, &cr);
  float dr, di; __sincosf(kx, &di, &dr);
  u16x8 pc, ps;
  for (int j = 0; j < 48; ++j) {
    const int h = h0 + j;
    CxT[(size_t)h*M2P + m2] = f2b(cr);
    SxT[(size_t)h*M2P + m2] = f2b(ci);
    pc[j&7] = f2b(cr); ps[j&7] = f2b(ci);
    if ((j&7) == 7) {
      *(u16x8*)(Am + (size_t)m2*192 + (h-7))         = pc;
      *(u16x8*)(Am + (size_t)(12672+m2)*192 + (h-7)) = ps;
    }
    rot(cr, ci, dr, di);
  }
}

// ---------------- forward: gemm1 + stage2 ----------------

// XT[n=(cb*192+w)][h] = bf16(x[b][h][w][c]),  cb = b*2+c
__global__ __launch_bounds__(256) void xprep_kernel(
    const float* __restrict__ x, unsigned short* __restrict__ XT) {
  const int idx = blockIdx.x*256 + threadIdx.x;
  if (idx >= 768*192) return;
  const int n = idx / 192, h = idx - n*192;
  const int cb = n / 192, w = n - cb*192;
  const int b = cb >> 1, c = cb & 1;
  XT[idx] = f2b(x[(((size_t)b*HH + h)*WW + w)*2 + c]);
}

// G[n][m] = sum_h Am[m][h] * XT[n][h]   (bf16 out, fp32 accum)
__global__ __launch_bounds__(256) void gemm1_kernel(
    const unsigned short* __restrict__ Am, const unsigned short* __restrict__ XT,
    unsigned short* __restrict__ G) {
  const int mt = blockIdx.x;          // 0..197
  const int nt = blockIdx.y;          // 0..3
  const int wv = threadIdx.x >> 6;
  const int lane = threadIdx.x & 63;
  const int r = lane & 15, kg = lane >> 4;
  const int mbase = mt*128 + (wv>>1)*64;
  const int nbase = nt*192 + (wv&1)*96;

  f32x4 acc[4][6];
  #pragma unroll
  for (int a = 0; a < 4; ++a)
    #pragma unroll
    for (int b = 0; b < 6; ++b) acc[a][b] = (f32x4){0.f,0.f,0.f,0.f};

  const unsigned short* Ap = Am + (size_t)(mbase + r)*192 + kg*8;
  const unsigned short* Bp = XT + (size_t)(nbase + r)*192 + kg*8;
  #pragma unroll
  for (int ks = 0; ks < 6; ++ks) {
    bf16x8 af[4], bfr[6];
    #pragma unroll
    for (int mf = 0; mf < 4; ++mf)
      af[mf] = *(const bf16x8*)(Ap + (size_t)mf*16*192 + ks*32);
    #pragma unroll
    for (int nf = 0; nf < 6; ++nf)
      bfr[nf] = *(const bf16x8*)(Bp + (size_t)nf*16*192 + ks*32);
    #pragma unroll
    for (int mf = 0; mf < 4; ++mf)
      #pragma unroll
      for (int nf = 0; nf < 6; ++nf)
        acc[mf][nf] = __builtin_amdgcn_mfma_f32_16x16x32_bf16(
            af[mf], bfr[nf], acc[mf][nf], 0, 0, 0);
  }
  #pragma unroll
  for (int mf = 0; mf < 4; ++mf)
    #pragma unroll
    for (int nf = 0; nf < 6; ++nf) {
      const int n = nbase + nf*16 + r;
      const int m = mbase + mf*16 + kg*4;
      ushort4 u = make_ushort4(f2b(acc[mf][nf][0]), f2b(acc[mf][nf][1]),
                               f2b(acc[mf][nf][2]), f2b(acc[mf][nf][3]));
      *(ushort4*)(G + (size_t)n*25344 + m) = u;
    }
}

// per m2: A1=sum_w Cr*Cy, A2=sum_w Si*Sy, A3=sum_w Si*Cy, A4=sum_w Cr*Sy
// combos: paired v2 in [1,63]: (2fA1, -2fA2, -2fA4, -2fA3); else (fkr,fkr,fki,fki)
// K2edge[v][d][cb][2] for t in {0,192}: weighted full-complex k per view.
__global__ __launch_bounds__(512) void stage2_kernel(
    const unsigned short* __restrict__ G, const float* __restrict__ points,
    const float* __restrict__ weights, float* __restrict__ combos,
    float* __restrict__ K2edge) {
  __shared__ float red[8][64][5];
  const int tid = threadIdx.x;
  const int wave = tid >> 6, lane = tid & 63;
  const int cb = wave >> 1, wh = wave & 1;
  const int m2 = blockIdx.x*64 + lane;
  const bool valid = (m2 < M2);
  float A1 = 0.f, A2 = 0.f, A3 = 0.f, A4 = 0.f;
  if (valid) {
    const int v2 = m2 / HALFT, t = m2 - v2*HALFT;
    const float ky = points[(v2*NSAMP + t)*2 + 1];
    const int w0 = wh*96;
    float cr, ci; __sincosf(ky*(float)(w0-96), &ci, &cr);
    float dr, di; __sincosf(ky, &di, &dr);
    const unsigned short* Gc = G + (size_t)(cb*192 + w0)*25344 + m2;
    const unsigned short* Gs = Gc + 12672;
    for (int w = 0; w < 96; ++w) {
      const float Cr = b2f(Gc[(size_t)w*25344]);
      const float Si = b2f(Gs[(size_t)w*25344]);
      A1 += Cr*cr; A4 += Cr*ci;
      A3 += Si*cr; A2 += Si*ci;
      rot(cr, ci, dr, di);
    }
  }
  red[wave][lane][0] = A1; red[wave][lane][1] = A2;
  red[wave][lane][2] = A3; red[wave][lane][3] = A4;
  __syncthreads();
  if (wh == 0 && valid) {
    A1 += red[wave+1][lane][0]; A2 += red[wave+1][lane][1];
    A3 += red[wave+1][lane][2]; A4 += red[wave+1][lane][3];
    const int v2 = m2 / HALFT, t = m2 - v2*HALFT;
    float f = weights[t] * (1.0f/36864.0f);
    if (t != 0 && t != 192) f *= 2.0f;
    const bool hp = (v2 >= 1 && v2 <= 63);
    float c0, c1, c2, c3;
    if (hp) {
      c0 =  2.f*f*A1; c1 = -2.f*f*A2; c2 = -2.f*f*A4; c3 = -2.f*f*A3;
    } else {
      const float kr = f*(A1 - A2), ki = -f*(A3 + A4);
      c0 = kr; c1 = kr; c2 = ki; c3 = ki;
    }
    combos[(cb*4+0)*M2P + m2] = c0;
    combos[(cb*4+1)*M2P + m2] = c1;
    combos[(cb*4+2)*M2P + m2] = c2;
    combos[(cb*4+3)*M2P + m2] = c3;
    if (t == 0 || t == 192) {
      const int d = (t == 0) ? 0 : 1;
      float* e = K2edge + ((v2*2 + d)*4 + cb)*2;
      e[0] = f*(A1 - A2); e[1] = -f*(A3 + A4);
      if (hp) {
        float* e2 = K2edge + (((128 - v2)*2 + d)*4 + cb)*2;
        e2[0] = f*(A1 + A2); e2[1] = f*(A3 - A4);
      }
    }
  }
}

// ---------------- adjoint (validated R3) ----------------

// A[j=(cb,h)][KTOT]: P = c0*cx - c3*sx ; Q = -(c1*sx + c2*cx)
__global__ __launch_bounds__(256) void tmat_kernel(
    const float* __restrict__ combos, const unsigned short* __restrict__ CxT,
    const unsigned short* __restrict__ SxT, unsigned short* __restrict__ A) {
  const int m2 = blockIdx.x*256 + threadIdx.x;
  if (m2 >= M2P) return;
  const int j = blockIdx.y;
  unsigned short* Arow = A + (size_t)j*KTOT;
  if (m2 >= M2) { Arow[m2] = 0; Arow[M2P + m2] = 0; return; }
  const int cb = j / 192, h = j - cb*192;
  const float cx = b2f(CxT[(size_t)h*M2P + m2]);
  const float sx = b2f(SxT[(size_t)h*M2P + m2]);
  const float c0 = combos[(cb*4+0)*M2P + m2];
  const float c1 = combos[(cb*4+1)*M2P + m2];
  const float c2 = combos[(cb*4+2)*M2P + m2];
  const float c3 = combos[(cb*4+3)*M2P + m2];
  Arow[m2]       = f2b(c0*cx - c3*sx);
  Arow[M2P + m2] = f2b(-(c1*sx + c2*cx));
}

__global__ __launch_bounds__(256) void adj_gemm(
    const unsigned short* __restrict__ A, const unsigned short* __restrict__ BT,
    float* __restrict__ partials) {
  const int mt = blockIdx.x;   // 0..5
  const int kc = blockIdx.y;   // 0..32
  const int wv = threadIdx.x >> 6;
  const int lane = threadIdx.x & 63;
  const int r = lane & 15, kg = lane >> 4;
  const int jbase = mt*128 + (wv>>1)*64;
  const int wbase = (wv&1)*96;
  const int kb = kc*768 + kg*8;

  f32x4 acc[4][6];
  #pragma unroll
  for (int a = 0; a < 4; ++a)
    #pragma unroll
    for (int b = 0; b < 6; ++b) acc[a][b] = (f32x4){0.f,0.f,0.f,0.f};

  const unsigned short* Ap = A + (size_t)(jbase + r)*KTOT + kb;
  const unsigned short* Bp = BT + (size_t)(wbase + r)*KTOT + kb;
  for (int ks = 0; ks < 24; ++ks) {
    bf16x8 af[4], bfr[6];
    #pragma unroll
    for (int mf = 0; mf < 4; ++mf)
      af[mf] = *(const bf16x8*)(Ap + (size_t)mf*16*KTOT + ks*32);
    #pragma unroll
    for (int nf = 0; nf < 6; ++nf)
      bfr[nf] = *(const bf16x8*)(Bp + (size_t)nf*16*KTOT + ks*32);
    #pragma unroll
    for (int mf = 0; mf < 4; ++mf)
      #pragma unroll
      for (int nf = 0; nf < 6; ++nf)
        acc[mf][nf] = __builtin_amdgcn_mfma_f32_16x16x32_bf16(
            af[mf], bfr[nf], acc[mf][nf], 0, 0, 0);
  }
  float* base = partials + (size_t)kc*192*768;
  #pragma unroll
  for (int mf = 0; mf < 4; ++mf)
    #pragma unroll
    for (int nf = 0; nf < 6; ++nf) {
      const int w = wbase + nf*16 + r;
      const int j = jbase + mf*16 + kg*4;
      *(f32x4*)(base + (size_t)w*768 + j) = acc[mf][nf];
    }
}

// imag part: only unpaired samples (t in {0,192}, all 128 views)
__global__ __launch_bounds__(256) void im_kernel(
    const unsigned short* __restrict__ BT, const unsigned short* __restrict__ CxT,
    const unsigned short* __restrict__ SxT, const float* __restrict__ K2edge,
    float* __restrict__ imb) {
  __shared__ float cxs[130][16], sxs[130][16], cys[130][16], sys[130][16];
  const int bx = blockIdx.x;
  const int h0 = (bx/12)*16, w0 = (bx%12)*16;
  const int tid = threadIdx.x;
  for (int i = tid; i < 130*16; i += 256) {
    const int s = i >> 4, e = i & 15;
    const int v2 = s >> 1, tt = (s & 1)*192;
    const int kap = v2*HALFT + tt;
    cxs[s][e] = b2f(CxT[(size_t)(h0+e)*M2P + kap]);
    sxs[s][e] = b2f(SxT[(size_t)(h0+e)*M2P + kap]);
    cys[s][e] = b2f(BT[(size_t)(w0+e)*KTOT + kap]);
    sys[s][e] = b2f(BT[(size_t)(w0+e)*KTOT + M2P + kap]);
  }
  __syncthreads();
  const int hi = tid >> 4, wi = tid & 15;
  float im[4] = {0,0,0,0};
  for (int v = 0; v < 128; ++v) {
    const int v2 = (v <= 64) ? v : 128 - v;
    const float sg = (v <= 64) ? 1.f : -1.f;
    #pragma unroll
    for (int d = 0; d < 2; ++d) {
      const int s = v2*2 + d;
      const float cx = cxs[s][hi], sx = sg*sxs[s][hi];
      const float cy = cys[s][wi], sy = sys[s][wi];
      const float t1 = cx*sy + sx*cy;
      const float t2 = cx*cy - sx*sy;
      const int idx = (v*2 + d)*8;
      #pragma unroll
      for (int cb = 0; cb < 4; ++cb)
        im[cb] += K2edge[idx + cb*2]*t1 + K2edge[idx + cb*2 + 1]*t2;
    }
  }
  const int pix = (h0+hi)*192 + (w0+wi);
  *(float4*)(imb + pix*4) = make_float4(im[0], im[1], im[2], im[3]);
}

__global__ __launch_bounds__(256) void out_new_kernel(
    const float* __restrict__ partials, const float* __restrict__ imb,
    float* __restrict__ out) {
  const int g = blockIdx.x*256 + threadIdx.x;
  const int w = g / 768, cbh = g - w*768;
  const int cb = cbh / 192, h = cbh - cb*192;
  float re = 0.f;
  for (int kc = 0; kc < NSPLITK; ++kc)
    re += partials[(size_t)kc*147456 + g];
  const float im = imb[(h*192 + w)*4 + cb];
  const float mag = sqrtf(re*re + im*im);
  const int b = cb >> 1, c = cb & 1;
  out[((size_t)b*NPIX + h*192 + w)*2 + c] = mag;
}

// ---------------- fallback (r2, validated) ----------------

template <int HPER>
__global__ __launch_bounds__(192) void fwd_kernel(
    const float* __restrict__ x, const float* __restrict__ points,
    float* __restrict__ kpart) {
  const int v = blockIdx.x;
  const int split = blockIdx.y;
  const int t = threadIdx.x;
  const int m = v*NSAMP + t;
  const float kx = points[2*m+0];
  const float ky = points[2*m+1];
  const int h0 = split*HPER;

  float kr[4] = {0,0,0,0}, ki[4] = {0,0,0,0};
  float cyr, cyi; __sincosf(96.0f*ky, &cyi, &cyr);
  float dyr, dyi; __sincosf(-ky, &dyi, &dyr);
  float cx0r, cx0i; __sincosf(kx*(float)(96-h0), &cx0i, &cx0r);
  float dxr, dxi; __sincosf(-kx, &dxi, &dxr);

  for (int wp = 0; wp < 96; ++wp) {
    const int w0 = wp*2;
    float g0r[4]={0,0,0,0}, g0i[4]={0,0,0,0};
    float g1r[4]={0,0,0,0}, g1i[4]={0,0,0,0};
    float cxr = cx0r, cxi = cx0i;
    const float* p0 = x + (h0*WW + w0)*2;
    const float* p1 = p0 + HH*WW*2;
    #pragma unroll 4
    for (int h = 0; h < HPER; ++h) {
      float4 a = *(const float4*)(p0 + h*(WW*2));
      float4 b = *(const float4*)(p1 + h*(WW*2));
      g0r[0] += a.x*cxr; g0i[0] += a.x*cxi;
      g0r[1] += a.y*cxr; g0i[1] += a.y*cxi;
      g1r[0] += a.z*cxr; g1i[0] += a.z*cxi;
      g1r[1] += a.w*cxr; g1i[1] += a.w*cxi;
      g0r[2] += b.x*cxr; g0i[2] += b.x*cxi;
      g0r[3] += b.y*cxr; g0i[3] += b.y*cxi;
      g1r[2] += b.z*cxr; g1i[2] += b.z*cxi;
      g1r[3] += b.w*cxr; g1i[3] += b.w*cxi;
      rot(cxr, cxi, dxr, dxi);
    }
    #pragma unroll
    for (int cb = 0; cb < 4; ++cb) {
      kr[cb] += g0r[cb]*cyr - g0i[cb]*cyi;
      ki[cb] += g0r[cb]*cyi + g0i[cb]*cyr;
    }
    rot(cyr, cyi, dyr, dyi);
    #pragma unroll
    for (int cb = 0; cb < 4; ++cb) {
      kr[cb] += g1r[cb]*cyr - g1i[cb]*cyi;
      ki[cb] += g1r[cb]*cyi + g1i[cb]*cyr;
    }
    rot(cyr, cyi, dyr, dyi);
  }
  float* o = kpart + (((split*NVIEWS + v)*192 + t)*4)*2;
  #pragma unroll
  for (int cb = 0; cb < 4; ++cb) { o[2*cb] = kr[cb]; o[2*cb+1] = ki[cb]; }
}

__global__ __launch_bounds__(256) void dc_kernel(
    const float* __restrict__ x, float* __restrict__ dcsum) {
  const int tid = threadIdx.x;
  float s0=0.f, s1=0.f, s2=0.f, s3=0.f;
  for (int i = tid; i < NPIX; i += 256) {
    float2 a = *(const float2*)(x + i*2);
    float2 b = *(const float2*)(x + HH*WW*2 + i*2);
    s0 += a.x; s1 += a.y; s2 += b.x; s3 += b.y;
  }
  #pragma unroll
  for (int off = 32; off > 0; off >>= 1) {
    s0 += __shfl_down(s0, off);
    s1 += __shfl_down(s1, off);
    s2 += __shfl_down(s2, off);
    s3 += __shfl_down(s3, off);
  }
  __shared__ float red[4][4];
  const int wv = tid >> 6, ln = tid & 63;
  if (ln == 0) { red[0][wv]=s0; red[1][wv]=s1; red[2][wv]=s2; red[3][wv]=s3; }
  __syncthreads();
  if (tid < 4) {
    float tot = red[tid][0]+red[tid][1]+red[tid][2]+red[tid][3];
    dcsum[2*tid] = tot; dcsum[2*tid+1] = 0.0f;
  }
}

__global__ __launch_bounds__(256) void combine_kernel(
    const float* __restrict__ kpart, const float* __restrict__ dcsum,
    const float* __restrict__ weights, float* __restrict__ K2, int nsplit) {
  const int idx = blockIdx.x*256 + threadIdx.x;
  if (idx >= NVIEWS*HALFT) return;
  const int v = idx / HALFT, t = idx % HALFT;
  float f = weights[t] * (1.0f/36864.0f);
  if (t != 0 && t != 192) f *= 2.0f;
  float o[8];
  if (t == 192) {
    #pragma unroll
    for (int cb = 0; cb < 4; ++cb) { o[2*cb] = f*dcsum[2*cb]; o[2*cb+1] = f*dcsum[2*cb+1]; }
  } else {
    #pragma unroll
    for (int cb = 0; cb < 4; ++cb) {
      float ar = 0.f, ai = 0.f;
      for (int s = 0; s < nsplit; ++s) {
        const float* p = kpart + (((s*NVIEWS + v)*192 + t)*4 + cb)*2;
        ar += p[0]; ai += p[1];
      }
      o[2*cb] = f*ar; o[2*cb+1] = f*ai;
    }
  }
  float* q = K2 + idx*8;
  #pragma unroll
  for (int j = 0; j < 8; ++j) q[j] = o[j];
}

template <int VPC>
__global__ __launch_bounds__(256) void adj_kernel(
    const float* __restrict__ K2, const float* __restrict__ points,
    float* __restrict__ imgpart) {
  const int pix = blockIdx.x*256 + threadIdx.x;
  const int chunk = blockIdx.y;
  const float nh = (float)(pix / WW - 96);
  const float nw = (float)(pix % WW - 96);
  float re[4] = {0,0,0,0}, im[4] = {0,0,0,0};
  const float INVPI = 0.3183098861837907f;
  const float PI192 = 3.14159265358979f / 192.0f;
  for (int v = chunk*VPC; v < chunk*VPC + VPC; ++v) {
    const float ct = -points[2*(v*NSAMP)+0] * INVPI;
    const float st = -points[2*(v*NSAMP)+1] * INVPI;
    const float alpha = ct*nh + st*nw;
    const float delta = alpha * PI192;
    float dr, di; __sincosf(delta, &di, &dr);
    float c0r, c0i; __sincosf(-192.0f*delta, &c0i, &c0r);
    const float* Kv = K2 + v*HALFT*8;
    #pragma unroll
    for (int cb = 0; cb < 4; ++cb) {
      float a = Kv[2*cb], b = Kv[2*cb+1];
      re[cb] += a*c0r - b*c0i;
      im[cb] += a*c0i + b*c0r;
    }
    float d2r = dr*dr - di*di, d2i = 2.0f*dr*di;
    float ar = c0r*dr - c0i*di, ai = c0r*di + c0i*dr;
    float br = ar*dr - ai*di,  bi = ar*di + ai*dr;
    for (int i = 0; i < 95; ++i) {
      const float* ka = Kv + (2*i+1)*8;
      const float* kb = Kv + (2*i+2)*8;
      #pragma unroll
      for (int cb = 0; cb < 4; ++cb)
        re[cb] += ka[2*cb]*ar - ka[2*cb+1]*ai;
      #pragma unroll
      for (int cb = 0; cb < 4; ++cb)
        re[cb] += kb[2*cb]*br - kb[2*cb+1]*bi;
      rot(ar, ai, d2r, d2i);
      rot(br, bi, d2r, d2i);
    }
    {
      const float* ka = Kv + 191*8;
      #pragma unroll
      for (int cb = 0; cb < 4; ++cb)
        re[cb] += ka[2*cb]*ar - ka[2*cb+1]*ai;
    }
    const float* kd = Kv + 192*8;
    #pragma unroll
    for (int cb = 0; cb < 4; ++cb) { re[cb] += kd[2*cb]; im[cb] += kd[2*cb+1]; }
  }
  float* o = imgpart + (chunk*NPIX + pix)*8;
  #pragma unroll
  for (int cb = 0; cb < 4; ++cb) { o[2*cb] = re[cb]; o[2*cb+1] = im[cb]; }
}

__global__ __launch_bounds__(256) void out_fb_kernel(
    const float* __restrict__ imgpart, float* __restrict__ out, int nchunk) {
  const int pix = blockIdx.x*256 + threadIdx.x;
  float re[4] = {0,0,0,0}, im[4] = {0,0,0,0};
  for (int ch = 0; ch < nchunk; ++ch) {
    const float* p = imgpart + (ch*NPIX + pix)*8;
    #pragma unroll
    for (int cb = 0; cb < 4; ++cb) { re[cb] += p[2*cb]; im[cb] += p[2*cb+1]; }
  }
  #pragma unroll
  for (int b = 0; b < 2; ++b)
    #pragma unroll
    for (int c = 0; c < 2; ++c) {
      const int cb = b*2 + c;
      out[(b*NPIX + pix)*2 + c] = sqrtf(re[cb]*re[cb] + im[cb]*im[cb]);
    }
}

extern "C" void kernel_launch(void* const* d_in, const int* in_sizes, int n_in,
                              void* d_out, int out_size, void* d_ws, size_t ws_size,
                              hipStream_t stream) {
  const float* x       = (const float*)d_in[0];
  const float* points  = (const float*)d_in[1];
  const float* weights = (const float*)d_in[2];
  float* out = (float*)d_out;

  const size_t NEED = 79265792ull;
  if (ws_size >= NEED) {
    char* wsb = (char*)d_ws;
    unsigned short* BT   = (unsigned short*)(wsb + 0);          //  9,732,096
    unsigned short* CxT  = (unsigned short*)(wsb + 9732096);    //  4,866,048
    unsigned short* SxT  = (unsigned short*)(wsb + 14598144);   //  4,866,048
    float* combos        = (float*)(wsb + 19464192);            //    811,008
    float* K2edge        = (float*)(wsb + 20275200);            //      8,192
    char* S              = wsb + 20283392;                      // 58,982,400
    // phase A
    unsigned short* Am   = (unsigned short*)(S + 0);            //  9,732,096
    unsigned short* XT   = (unsigned short*)(S + 9732096);      //    294,912
    unsigned short* G    = (unsigned short*)(S + 10027008);     // 38,928,384
    // phase B (overlaps phase A; stream-ordered)
    unsigned short* Aadj = (unsigned short*)(S + 0);            // 38,928,384
    float* partials      = (float*)(S + 38928384);              // 19,464,192
    float* imb           = (float*)(S + 58392576);              //    589,824

    hipMemsetAsync(Am, 0, 9732096, stream);   // zero pad rows for gemm1
    ygen_kernel<<<dim3(65,4), 256, 0, stream>>>(points, BT);
    xgen_kernel<<<dim3(65,4), 256, 0, stream>>>(points, CxT, SxT, Am);
    xprep_kernel<<<576, 256, 0, stream>>>(x, XT);
    gemm1_kernel<<<dim3(198,4), 256, 0, stream>>>(Am, XT, G);
    stage2_kernel<<<198, 512, 0, stream>>>(G, points, weights, combos, K2edge);
    tmat_kernel<<<dim3((M2P + 255)/256, 768), 256, 0, stream>>>(
        combos, CxT, SxT, Aadj);
    adj_gemm<<<dim3(6, NSPLITK), 256, 0, stream>>>(Aadj, BT, partials);
    im_kernel<<<144, 256, 0, stream>>>(BT, CxT, SxT, K2edge, imb);
    out_new_kernel<<<(192*768)/256, 256, 0, stream>>>(partials, imb, out);
  } else {
    // r2 fallback path
    float* ws = (float*)d_ws;
    const size_t ws_floats = ws_size / sizeof(float);
    int nsplit = 16, nchunk = 16;
    auto need = [&](int ns, int nc) -> size_t {
      return (size_t)ns*196608 + 8 + 197632 + (size_t)nc*294912;
    };
    while (need(nsplit, nchunk) > ws_floats && nchunk > 1) nchunk >>= 1;
    while (need(nsplit, nchunk) > ws_floats && nsplit > 1) nsplit >>= 1;

    float* kpart   = ws;
    float* dcsum   = kpart + (size_t)nsplit*196608;
    float* K2      = dcsum + 8;
    float* imgpart = K2 + 197632;

    switch (nsplit) {
      case 16: fwd_kernel<12><<<dim3(NVIEWS,16), 192, 0, stream>>>(x, points, kpart); break;
      case 8:  fwd_kernel<24><<<dim3(NVIEWS,8),  192, 0, stream>>>(x, points, kpart); break;
      case 4:  fwd_kernel<48><<<dim3(NVIEWS,4),  192, 0, stream>>>(x, points, kpart); break;
      case 2:  fwd_kernel<96><<<dim3(NVIEWS,2),  192, 0, stream>>>(x, points, kpart); break;
      default: fwd_kernel<192><<<dim3(NVIEWS,1), 192, 0, stream>>>(x, points, kpart); break;
    }
    dc_kernel<<<1, 256, 0, stream>>>(x, dcsum);
    combine_kernel<<<(NVIEWS*HALFT + 255)/256, 256, 0, stream>>>(
        kpart, dcsum, weights, K2, nsplit);
    switch (nchunk) {
      case 16: adj_kernel<8>  <<<dim3(NPIX/256,16), 256, 0, stream>>>(K2, points, imgpart); break;
      case 8:  adj_kernel<16> <<<dim3(NPIX/256,8),  256, 0, stream>>>(K2, points, imgpart); break;
      case 4:  adj_kernel<32> <<<dim3(NPIX/256,4),  256, 0, stream>>>(K2, points, imgpart); break;
      case 2:  adj_kernel<64> <<<dim3(NPIX/256,2),  256, 0, stream>>>(K2, points, imgpart); break;
      default: adj_kernel<128><<<dim3(NPIX/256,1),  256, 0, stream>>>(K2, points, imgpart); break;
    }
    out_fb_kernel<<<NPIX/256, 256, 0, stream>>>(imgpart, out, nchunk);
  }
}

// Round 5
// 158.788 us; speedup vs baseline: 8.4254x; 1.2774x over previous
//
#include <hip/hip_runtime.h>
#include <math.h>

// KSpaceResampling: type-2 NUDFT -> ramp weights -> type-1 adjoint -> abs
// R5: im_kernel fix — drop the exactly-zero t=192 contribution (DC sample is
// real, phase=1), split the 128-view loop across 4 thread-groups, 8x8 pixel
// tiles (576 blocks). GEMM pipeline unchanged (validated R3/R4).

#define HH 192
#define WW 192
#define NVIEWS 128
#define NSAMP 384
#define NPIX (HH*WW)      // 36864
#define HALFT 193         // stored t = 0..192
#define M2 12545          // 65 * 193  (v2 in [0,64])
#define M2P 12672         // padded
#define KTOT 25344        // 2 * M2P   (adjoint GEMM K: Cy-part ; Sy-part)
#define NSPLITK 33        // adjoint GEMM K-split (25344/33 = 768)

typedef __attribute__((ext_vector_type(8))) short bf16x8;
typedef __attribute__((ext_vector_type(4))) float f32x4;
typedef __attribute__((ext_vector_type(8))) unsigned short u16x8;

__device__ __forceinline__ void rot(float& cr, float& ci, float dr, float di) {
  float nr = cr*dr - ci*di;
  float ni = cr*di + ci*dr;
  cr = nr; ci = ni;
}
__device__ __forceinline__ unsigned short f2b(float f) {
  unsigned int u = __float_as_uint(f);
  u += 0x7fffu + ((u >> 16) & 1u);
  return (unsigned short)(u >> 16);
}
__device__ __forceinline__ float b2f(unsigned short h) {
  return __uint_as_float(((unsigned int)h) << 16);
}

// ---------------- phase tables ----------------

// BT[w][KTOT]: cols [0,M2) = cos(ky*nw), cols [M2P,M2P+M2) = sin(ky*nw)
__global__ __launch_bounds__(256) void ygen_kernel(
    const float* __restrict__ points, unsigned short* __restrict__ BT) {
  const int v2 = blockIdx.x;
  const int wsplit = blockIdx.y;       // 0..3
  const int t = threadIdx.x;
  if (t >= HALFT) return;
  const float ky = points[(v2*NSAMP + t)*2 + 1];
  const int kap = v2*HALFT + t;
  const int w0 = wsplit*48;
  float cr, ci; __sincosf(ky*(float)(w0-96), &ci, &cr);
  float dr, di; __sincosf(ky, &di, &dr);
  for (int j = 0; j < 48; ++j) {
    BT[(size_t)(w0+j)*KTOT + kap]       = f2b(cr);
    BT[(size_t)(w0+j)*KTOT + M2P + kap] = f2b(ci);
    rot(cr, ci, dr, di);
  }
}

// CxT[h][M2P]=cos(kx*nh), SxT[h][M2P]=sin(kx*nh)  (h-major, for tmat/im)
// Am[m][192]: rows [0,12672) = Cx, rows [12672,25344) = Sx (m2-major, gemm1 A)
__global__ __launch_bounds__(256) void xgen_kernel(
    const float* __restrict__ points, unsigned short* __restrict__ CxT,
    unsigned short* __restrict__ SxT, unsigned short* __restrict__ Am) {
  const int v2 = blockIdx.x;
  const int hsplit = blockIdx.y;       // 0..3
  const int t = threadIdx.x;
  if (t >= HALFT) return;
  const float kx = points[(v2*NSAMP + t)*2 + 0];
  const int m2 = v2*HALFT + t;
  const int h0 = hsplit*48;
  float cr, ci; __sincosf(kx*(float)(h0-96), &ci, &cr);
  float dr, di; __sincosf(kx, &di, &dr);
  u16x8 pc, ps;
  for (int j = 0; j < 48; ++j) {
    const int h = h0 + j;
    CxT[(size_t)h*M2P + m2] = f2b(cr);
    SxT[(size_t)h*M2P + m2] = f2b(ci);
    pc[j&7] = f2b(cr); ps[j&7] = f2b(ci);
    if ((j&7) == 7) {
      *(u16x8*)(Am + (size_t)m2*192 + (h-7))         = pc;
      *(u16x8*)(Am + (size_t)(12672+m2)*192 + (h-7)) = ps;
    }
    rot(cr, ci, dr, di);
  }
}

// ---------------- forward: gemm1 + stage2 ----------------

// XT[n=(cb*192+w)][h] = bf16(x[b][h][w][c]),  cb = b*2+c
__global__ __launch_bounds__(256) void xprep_kernel(
    const float* __restrict__ x, unsigned short* __restrict__ XT) {
  const int idx = blockIdx.x*256 + threadIdx.x;
  if (idx >= 768*192) return;
  const int n = idx / 192, h = idx - n*192;
  const int cb = n / 192, w = n - cb*192;
  const int b = cb >> 1, c = cb & 1;
  XT[idx] = f2b(x[(((size_t)b*HH + h)*WW + w)*2 + c]);
}

// G[n][m] = sum_h Am[m][h] * XT[n][h]   (bf16 out, fp32 accum)
__global__ __launch_bounds__(256) void gemm1_kernel(
    const unsigned short* __restrict__ Am, const unsigned short* __restrict__ XT,
    unsigned short* __restrict__ G) {
  const int mt = blockIdx.x;          // 0..197
  const int nt = blockIdx.y;          // 0..3
  const int wv = threadIdx.x >> 6;
  const int lane = threadIdx.x & 63;
  const int r = lane & 15, kg = lane >> 4;
  const int mbase = mt*128 + (wv>>1)*64;
  const int nbase = nt*192 + (wv&1)*96;

  f32x4 acc[4][6];
  #pragma unroll
  for (int a = 0; a < 4; ++a)
    #pragma unroll
    for (int b = 0; b < 6; ++b) acc[a][b] = (f32x4){0.f,0.f,0.f,0.f};

  const unsigned short* Ap = Am + (size_t)(mbase + r)*192 + kg*8;
  const unsigned short* Bp = XT + (size_t)(nbase + r)*192 + kg*8;
  #pragma unroll
  for (int ks = 0; ks < 6; ++ks) {
    bf16x8 af[4], bfr[6];
    #pragma unroll
    for (int mf = 0; mf < 4; ++mf)
      af[mf] = *(const bf16x8*)(Ap + (size_t)mf*16*192 + ks*32);
    #pragma unroll
    for (int nf = 0; nf < 6; ++nf)
      bfr[nf] = *(const bf16x8*)(Bp + (size_t)nf*16*192 + ks*32);
    #pragma unroll
    for (int mf = 0; mf < 4; ++mf)
      #pragma unroll
      for (int nf = 0; nf < 6; ++nf)
        acc[mf][nf] = __builtin_amdgcn_mfma_f32_16x16x32_bf16(
            af[mf], bfr[nf], acc[mf][nf], 0, 0, 0);
  }
  #pragma unroll
  for (int mf = 0; mf < 4; ++mf)
    #pragma unroll
    for (int nf = 0; nf < 6; ++nf) {
      const int n = nbase + nf*16 + r;
      const int m = mbase + mf*16 + kg*4;
      ushort4 u = make_ushort4(f2b(acc[mf][nf][0]), f2b(acc[mf][nf][1]),
                               f2b(acc[mf][nf][2]), f2b(acc[mf][nf][3]));
      *(ushort4*)(G + (size_t)n*25344 + m) = u;
    }
}

// per m2: A1=sum_w Cr*Cy, A2=sum_w Si*Sy, A3=sum_w Si*Cy, A4=sum_w Cr*Sy
// combos: paired v2 in [1,63]: (2fA1, -2fA2, -2fA4, -2fA3); else (fkr,fkr,fki,fki)
// K2edge[v][d][cb][2] for t in {0,192}: weighted full-complex k per view.
__global__ __launch_bounds__(512) void stage2_kernel(
    const unsigned short* __restrict__ G, const float* __restrict__ points,
    const float* __restrict__ weights, float* __restrict__ combos,
    float* __restrict__ K2edge) {
  __shared__ float red[8][64][5];
  const int tid = threadIdx.x;
  const int wave = tid >> 6, lane = tid & 63;
  const int cb = wave >> 1, wh = wave & 1;
  const int m2 = blockIdx.x*64 + lane;
  const bool valid = (m2 < M2);
  float A1 = 0.f, A2 = 0.f, A3 = 0.f, A4 = 0.f;
  if (valid) {
    const int v2 = m2 / HALFT, t = m2 - v2*HALFT;
    const float ky = points[(v2*NSAMP + t)*2 + 1];
    const int w0 = wh*96;
    float cr, ci; __sincosf(ky*(float)(w0-96), &ci, &cr);
    float dr, di; __sincosf(ky, &di, &dr);
    const unsigned short* Gc = G + (size_t)(cb*192 + w0)*25344 + m2;
    const unsigned short* Gs = Gc + 12672;
    for (int w = 0; w < 96; ++w) {
      const float Cr = b2f(Gc[(size_t)w*25344]);
      const float Si = b2f(Gs[(size_t)w*25344]);
      A1 += Cr*cr; A4 += Cr*ci;
      A3 += Si*cr; A2 += Si*ci;
      rot(cr, ci, dr, di);
    }
  }
  red[wave][lane][0] = A1; red[wave][lane][1] = A2;
  red[wave][lane][2] = A3; red[wave][lane][3] = A4;
  __syncthreads();
  if (wh == 0 && valid) {
    A1 += red[wave+1][lane][0]; A2 += red[wave+1][lane][1];
    A3 += red[wave+1][lane][2]; A4 += red[wave+1][lane][3];
    const int v2 = m2 / HALFT, t = m2 - v2*HALFT;
    float f = weights[t] * (1.0f/36864.0f);
    if (t != 0 && t != 192) f *= 2.0f;
    const bool hp = (v2 >= 1 && v2 <= 63);
    float c0, c1, c2, c3;
    if (hp) {
      c0 =  2.f*f*A1; c1 = -2.f*f*A2; c2 = -2.f*f*A4; c3 = -2.f*f*A3;
    } else {
      const float kr = f*(A1 - A2), ki = -f*(A3 + A4);
      c0 = kr; c1 = kr; c2 = ki; c3 = ki;
    }
    combos[(cb*4+0)*M2P + m2] = c0;
    combos[(cb*4+1)*M2P + m2] = c1;
    combos[(cb*4+2)*M2P + m2] = c2;
    combos[(cb*4+3)*M2P + m2] = c3;
    if (t == 0 || t == 192) {
      const int d = (t == 0) ? 0 : 1;
      float* e = K2edge + ((v2*2 + d)*4 + cb)*2;
      e[0] = f*(A1 - A2); e[1] = -f*(A3 + A4);
      if (hp) {
        float* e2 = K2edge + (((128 - v2)*2 + d)*4 + cb)*2;
        e2[0] = f*(A1 + A2); e2[1] = f*(A3 - A4);
      }
    }
  }
}

// ---------------- adjoint (validated R3) ----------------

// A[j=(cb,h)][KTOT]: P = c0*cx - c3*sx ; Q = -(c1*sx + c2*cx)
__global__ __launch_bounds__(256) void tmat_kernel(
    const float* __restrict__ combos, const unsigned short* __restrict__ CxT,
    const unsigned short* __restrict__ SxT, unsigned short* __restrict__ A) {
  const int m2 = blockIdx.x*256 + threadIdx.x;
  if (m2 >= M2P) return;
  const int j = blockIdx.y;
  unsigned short* Arow = A + (size_t)j*KTOT;
  if (m2 >= M2) { Arow[m2] = 0; Arow[M2P + m2] = 0; return; }
  const int cb = j / 192, h = j - cb*192;
  const float cx = b2f(CxT[(size_t)h*M2P + m2]);
  const float sx = b2f(SxT[(size_t)h*M2P + m2]);
  const float c0 = combos[(cb*4+0)*M2P + m2];
  const float c1 = combos[(cb*4+1)*M2P + m2];
  const float c2 = combos[(cb*4+2)*M2P + m2];
  const float c3 = combos[(cb*4+3)*M2P + m2];
  Arow[m2]       = f2b(c0*cx - c3*sx);
  Arow[M2P + m2] = f2b(-(c1*sx + c2*cx));
}

__global__ __launch_bounds__(256) void adj_gemm(
    const unsigned short* __restrict__ A, const unsigned short* __restrict__ BT,
    float* __restrict__ partials) {
  const int mt = blockIdx.x;   // 0..5
  const int kc = blockIdx.y;   // 0..32
  const int wv = threadIdx.x >> 6;
  const int lane = threadIdx.x & 63;
  const int r = lane & 15, kg = lane >> 4;
  const int jbase = mt*128 + (wv>>1)*64;
  const int wbase = (wv&1)*96;
  const int kb = kc*768 + kg*8;

  f32x4 acc[4][6];
  #pragma unroll
  for (int a = 0; a < 4; ++a)
    #pragma unroll
    for (int b = 0; b < 6; ++b) acc[a][b] = (f32x4){0.f,0.f,0.f,0.f};

  const unsigned short* Ap = A + (size_t)(jbase + r)*KTOT + kb;
  const unsigned short* Bp = BT + (size_t)(wbase + r)*KTOT + kb;
  for (int ks = 0; ks < 24; ++ks) {
    bf16x8 af[4], bfr[6];
    #pragma unroll
    for (int mf = 0; mf < 4; ++mf)
      af[mf] = *(const bf16x8*)(Ap + (size_t)mf*16*KTOT + ks*32);
    #pragma unroll
    for (int nf = 0; nf < 6; ++nf)
      bfr[nf] = *(const bf16x8*)(Bp + (size_t)nf*16*KTOT + ks*32);
    #pragma unroll
    for (int mf = 0; mf < 4; ++mf)
      #pragma unroll
      for (int nf = 0; nf < 6; ++nf)
        acc[mf][nf] = __builtin_amdgcn_mfma_f32_16x16x32_bf16(
            af[mf], bfr[nf], acc[mf][nf], 0, 0, 0);
  }
  float* base = partials + (size_t)kc*192*768;
  #pragma unroll
  for (int mf = 0; mf < 4; ++mf)
    #pragma unroll
    for (int nf = 0; nf < 6; ++nf) {
      const int w = wbase + nf*16 + r;
      const int j = jbase + mf*16 + kg*4;
      *(f32x4*)(base + (size_t)w*768 + j) = acc[mf][nf];
    }
}

// imag part: ONLY t=0 samples contribute (t=192 is DC: real k, phase 1 ->
// exactly zero imag, in both reference and our pipeline since sin(0)=0).
// 8x8 pixel tiles, 4 view-groups of 32 per block, LDS reduce.
__global__ __launch_bounds__(256) void im_kernel(
    const unsigned short* __restrict__ BT, const unsigned short* __restrict__ CxT,
    const unsigned short* __restrict__ SxT, const float* __restrict__ K2edge,
    float* __restrict__ imb) {
  __shared__ float cxs[65][8], sxs[65][8], cys[65][8], sys[65][8];
  __shared__ float red[4][64][4];
  const int bx = blockIdx.x;            // 576 = 24x24 tiles of 8x8 pixels
  const int h0 = (bx/24)*8, w0 = (bx%24)*8;
  const int tid = threadIdx.x;
  for (int i = tid; i < 65*8; i += 256) {
    const int v2 = i >> 3, e = i & 7;
    const int kap = v2*HALFT;           // t = 0
    cxs[v2][e] = b2f(CxT[(size_t)(h0+e)*M2P + kap]);
    sxs[v2][e] = b2f(SxT[(size_t)(h0+e)*M2P + kap]);
    cys[v2][e] = b2f(BT[(size_t)(w0+e)*KTOT + kap]);
    sys[v2][e] = b2f(BT[(size_t)(w0+e)*KTOT + M2P + kap]);
  }
  __syncthreads();
  const int g = tid >> 6, hi = (tid >> 3) & 7, wi = tid & 7;
  float im[4] = {0,0,0,0};
  for (int v = g*32; v < g*32 + 32; ++v) {
    const int v2 = (v <= 64) ? v : 128 - v;
    const float sg = (v <= 64) ? 1.f : -1.f;
    const float cx = cxs[v2][hi], sx = sg*sxs[v2][hi];
    const float cy = cys[v2][wi], sy = sys[v2][wi];
    const float t1 = cx*sy + sx*cy;     // Im phase coeff of Kr
    const float t2 = cx*cy - sx*sy;     // Im phase coeff of Ki
    const int idx = v*16;               // (v*2 + d=0)*8
    #pragma unroll
    for (int cb = 0; cb < 4; ++cb)
      im[cb] += K2edge[idx + cb*2]*t1 + K2edge[idx + cb*2 + 1]*t2;
  }
  const int p = tid & 63;
  #pragma unroll
  for (int cb = 0; cb < 4; ++cb) red[g][p][cb] = im[cb];
  __syncthreads();
  if (g == 0) {
    #pragma unroll
    for (int cb = 0; cb < 4; ++cb)
      im[cb] += red[1][p][cb] + red[2][p][cb] + red[3][p][cb];
    const int pix = (h0+hi)*192 + (w0+wi);
    *(float4*)(imb + pix*4) = make_float4(im[0], im[1], im[2], im[3]);
  }
}

__global__ __launch_bounds__(256) void out_new_kernel(
    const float* __restrict__ partials, const float* __restrict__ imb,
    float* __restrict__ out) {
  const int g = blockIdx.x*256 + threadIdx.x;
  const int w = g / 768, cbh = g - w*768;
  const int cb = cbh / 192, h = cbh - cb*192;
  float re = 0.f;
  for (int kc = 0; kc < NSPLITK; ++kc)
    re += partials[(size_t)kc*147456 + g];
  const float im = imb[(h*192 + w)*4 + cb];
  const float mag = sqrtf(re*re + im*im);
  const int b = cb >> 1, c = cb & 1;
  out[((size_t)b*NPIX + h*192 + w)*2 + c] = mag;
}

// ---------------- fallback (r2, validated) ----------------

template <int HPER>
__global__ __launch_bounds__(192) void fwd_kernel(
    const float* __restrict__ x, const float* __restrict__ points,
    float* __restrict__ kpart) {
  const int v = blockIdx.x;
  const int split = blockIdx.y;
  const int t = threadIdx.x;
  const int m = v*NSAMP + t;
  const float kx = points[2*m+0];
  const float ky = points[2*m+1];
  const int h0 = split*HPER;

  float kr[4] = {0,0,0,0}, ki[4] = {0,0,0,0};
  float cyr, cyi; __sincosf(96.0f*ky, &cyi, &cyr);
  float dyr, dyi; __sincosf(-ky, &dyi, &dyr);
  float cx0r, cx0i; __sincosf(kx*(float)(96-h0), &cx0i, &cx0r);
  float dxr, dxi; __sincosf(-kx, &dxi, &dxr);

  for (int wp = 0; wp < 96; ++wp) {
    const int w0 = wp*2;
    float g0r[4]={0,0,0,0}, g0i[4]={0,0,0,0};
    float g1r[4]={0,0,0,0}, g1i[4]={0,0,0,0};
    float cxr = cx0r, cxi = cx0i;
    const float* p0 = x + (h0*WW + w0)*2;
    const float* p1 = p0 + HH*WW*2;
    #pragma unroll 4
    for (int h = 0; h < HPER; ++h) {
      float4 a = *(const float4*)(p0 + h*(WW*2));
      float4 b = *(const float4*)(p1 + h*(WW*2));
      g0r[0] += a.x*cxr; g0i[0] += a.x*cxi;
      g0r[1] += a.y*cxr; g0i[1] += a.y*cxi;
      g1r[0] += a.z*cxr; g1i[0] += a.z*cxi;
      g1r[1] += a.w*cxr; g1i[1] += a.w*cxi;
      g0r[2] += b.x*cxr; g0i[2] += b.x*cxi;
      g0r[3] += b.y*cxr; g0i[3] += b.y*cxi;
      g1r[2] += b.z*cxr; g1i[2] += b.z*cxi;
      g1r[3] += b.w*cxr; g1i[3] += b.w*cxi;
      rot(cxr, cxi, dxr, dxi);
    }
    #pragma unroll
    for (int cb = 0; cb < 4; ++cb) {
      kr[cb] += g0r[cb]*cyr - g0i[cb]*cyi;
      ki[cb] += g0r[cb]*cyi + g0i[cb]*cyr;
    }
    rot(cyr, cyi, dyr, dyi);
    #pragma unroll
    for (int cb = 0; cb < 4; ++cb) {
      kr[cb] += g1r[cb]*cyr - g1i[cb]*cyi;
      ki[cb] += g1r[cb]*cyi + g1i[cb]*cyr;
    }
    rot(cyr, cyi, dyr, dyi);
  }
  float* o = kpart + (((split*NVIEWS + v)*192 + t)*4)*2;
  #pragma unroll
  for (int cb = 0; cb < 4; ++cb) { o[2*cb] = kr[cb]; o[2*cb+1] = ki[cb]; }
}

__global__ __launch_bounds__(256) void dc_kernel(
    const float* __restrict__ x, float* __restrict__ dcsum) {
  const int tid = threadIdx.x;
  float s0=0.f, s1=0.f, s2=0.f, s3=0.f;
  for (int i = tid; i < NPIX; i += 256) {
    float2 a = *(const float2*)(x + i*2);
    float2 b = *(const float2*)(x + HH*WW*2 + i*2);
    s0 += a.x; s1 += a.y; s2 += b.x; s3 += b.y;
  }
  #pragma unroll
  for (int off = 32; off > 0; off >>= 1) {
    s0 += __shfl_down(s0, off);
    s1 += __shfl_down(s1, off);
    s2 += __shfl_down(s2, off);
    s3 += __shfl_down(s3, off);
  }
  __shared__ float red[4][4];
  const int wv = tid >> 6, ln = tid & 63;
  if (ln == 0) { red[0][wv]=s0; red[1][wv]=s1; red[2][wv]=s2; red[3][wv]=s3; }
  __syncthreads();
  if (tid < 4) {
    float tot = red[tid][0]+red[tid][1]+red[tid][2]+red[tid][3];
    dcsum[2*tid] = tot; dcsum[2*tid+1] = 0.0f;
  }
}

__global__ __launch_bounds__(256) void combine_kernel(
    const float* __restrict__ kpart, const float* __restrict__ dcsum,
    const float* __restrict__ weights, float* __restrict__ K2, int nsplit) {
  const int idx = blockIdx.x*256 + threadIdx.x;
  if (idx >= NVIEWS*HALFT) return;
  const int v = idx / HALFT, t = idx % HALFT;
  float f = weights[t] * (1.0f/36864.0f);
  if (t != 0 && t != 192) f *= 2.0f;
  float o[8];
  if (t == 192) {
    #pragma unroll
    for (int cb = 0; cb < 4; ++cb) { o[2*cb] = f*dcsum[2*cb]; o[2*cb+1] = f*dcsum[2*cb+1]; }
  } else {
    #pragma unroll
    for (int cb = 0; cb < 4; ++cb) {
      float ar = 0.f, ai = 0.f;
      for (int s = 0; s < nsplit; ++s) {
        const float* p = kpart + (((s*NVIEWS + v)*192 + t)*4 + cb)*2;
        ar += p[0]; ai += p[1];
      }
      o[2*cb] = f*ar; o[2*cb+1] = f*ai;
    }
  }
  float* q = K2 + idx*8;
  #pragma unroll
  for (int j = 0; j < 8; ++j) q[j] = o[j];
}

template <int VPC>
__global__ __launch_bounds__(256) void adj_kernel(
    const float* __restrict__ K2, const float* __restrict__ points,
    float* __restrict__ imgpart) {
  const int pix = blockIdx.x*256 + threadIdx.x;
  const int chunk = blockIdx.y;
  const float nh = (float)(pix / WW - 96);
  const float nw = (float)(pix % WW - 96);
  float re[4] = {0,0,0,0}, im[4] = {0,0,0,0};
  const float INVPI = 0.3183098861837907f;
  const float PI192 = 3.14159265358979f / 192.0f;
  for (int v = chunk*VPC; v < chunk*VPC + VPC; ++v) {
    const float ct = -points[2*(v*NSAMP)+0] * INVPI;
    const float st = -points[2*(v*NSAMP)+1] * INVPI;
    const float alpha = ct*nh + st*nw;
    const float delta = alpha * PI192;
    float dr, di; __sincosf(delta, &di, &dr);
    float c0r, c0i; __sincosf(-192.0f*delta, &c0i, &c0r);
    const float* Kv = K2 + v*HALFT*8;
    #pragma unroll
    for (int cb = 0; cb < 4; ++cb) {
      float a = Kv[2*cb], b = Kv[2*cb+1];
      re[cb] += a*c0r - b*c0i;
      im[cb] += a*c0i + b*c0r;
    }
    float d2r = dr*dr - di*di, d2i = 2.0f*dr*di;
    float ar = c0r*dr - c0i*di, ai = c0r*di + c0i*dr;
    float br = ar*dr - ai*di,  bi = ar*di + ai*dr;
    for (int i = 0; i < 95; ++i) {
      const float* ka = Kv + (2*i+1)*8;
      const float* kb = Kv + (2*i+2)*8;
      #pragma unroll
      for (int cb = 0; cb < 4; ++cb)
        re[cb] += ka[2*cb]*ar - ka[2*cb+1]*ai;
      #pragma unroll
      for (int cb = 0; cb < 4; ++cb)
        re[cb] += kb[2*cb]*br - kb[2*cb+1]*bi;
      rot(ar, ai, d2r, d2i);
      rot(br, bi, d2r, d2i);
    }
    {
      const float* ka = Kv + 191*8;
      #pragma unroll
      for (int cb = 0; cb < 4; ++cb)
        re[cb] += ka[2*cb]*ar - ka[2*cb+1]*ai;
    }
    const float* kd = Kv + 192*8;
    #pragma unroll
    for (int cb = 0; cb < 4; ++cb) { re[cb] += kd[2*cb]; im[cb] += kd[2*cb+1]; }
  }
  float* o = imgpart + (chunk*NPIX + pix)*8;
  #pragma unroll
  for (int cb = 0; cb < 4; ++cb) { o[2*cb] = re[cb]; o[2*cb+1] = im[cb]; }
}

__global__ __launch_bounds__(256) void out_fb_kernel(
    const float* __restrict__ imgpart, float* __restrict__ out, int nchunk) {
  const int pix = blockIdx.x*256 + threadIdx.x;
  float re[4] = {0,0,0,0}, im[4] = {0,0,0,0};
  for (int ch = 0; ch < nchunk; ++ch) {
    const float* p = imgpart + (ch*NPIX + pix)*8;
    #pragma unroll
    for (int cb = 0; cb < 4; ++cb) { re[cb] += p[2*cb]; im[cb] += p[2*cb+1]; }
  }
  #pragma unroll
  for (int b = 0; b < 2; ++b)
    #pragma unroll
    for (int c = 0; c < 2; ++c) {
      const int cb = b*2 + c;
      out[(b*NPIX + pix)*2 + c] = sqrtf(re[cb]*re[cb] + im[cb]*im[cb]);
    }
}

extern "C" void kernel_launch(void* const* d_in, const int* in_sizes, int n_in,
                              void* d_out, int out_size, void* d_ws, size_t ws_size,
                              hipStream_t stream) {
  const float* x       = (const float*)d_in[0];
  const float* points  = (const float*)d_in[1];
  const float* weights = (const float*)d_in[2];
  float* out = (float*)d_out;

  const size_t NEED = 79265792ull;
  if (ws_size >= NEED) {
    char* wsb = (char*)d_ws;
    unsigned short* BT   = (unsigned short*)(wsb + 0);          //  9,732,096
    unsigned short* CxT  = (unsigned short*)(wsb + 9732096);    //  4,866,048
    unsigned short* SxT  = (unsigned short*)(wsb + 14598144);   //  4,866,048
    float* combos        = (float*)(wsb + 19464192);            //    811,008
    float* K2edge        = (float*)(wsb + 20275200);            //      8,192
    char* S              = wsb + 20283392;                      // 58,982,400
    // phase A
    unsigned short* Am   = (unsigned short*)(S + 0);            //  9,732,096
    unsigned short* XT   = (unsigned short*)(S + 9732096);      //    294,912
    unsigned short* G    = (unsigned short*)(S + 10027008);     // 38,928,384
    // phase B (overlaps phase A; stream-ordered)
    unsigned short* Aadj = (unsigned short*)(S + 0);            // 38,928,384
    float* partials      = (float*)(S + 38928384);              // 19,464,192
    float* imb           = (float*)(S + 58392576);              //    589,824

    hipMemsetAsync(Am, 0, 9732096, stream);   // zero pad rows for gemm1
    ygen_kernel<<<dim3(65,4), 256, 0, stream>>>(points, BT);
    xgen_kernel<<<dim3(65,4), 256, 0, stream>>>(points, CxT, SxT, Am);
    xprep_kernel<<<576, 256, 0, stream>>>(x, XT);
    gemm1_kernel<<<dim3(198,4), 256, 0, stream>>>(Am, XT, G);
    stage2_kernel<<<198, 512, 0, stream>>>(G, points, weights, combos, K2edge);
    tmat_kernel<<<dim3((M2P + 255)/256, 768), 256, 0, stream>>>(
        combos, CxT, SxT, Aadj);
    adj_gemm<<<dim3(6, NSPLITK), 256, 0, stream>>>(Aadj, BT, partials);
    im_kernel<<<576, 256, 0, stream>>>(BT, CxT, SxT, K2edge, imb);
    out_new_kernel<<<(192*768)/256, 256, 0, stream>>>(partials, imb, out);
  } else {
    // r2 fallback path
    float* ws = (float*)d_ws;
    const size_t ws_floats = ws_size / sizeof(float);
    int nsplit = 16, nchunk = 16;
    auto need = [&](int ns, int nc) -> size_t {
      return (size_t)ns*196608 + 8 + 197632 + (size_t)nc*294912;
    };
    while (need(nsplit, nchunk) > ws_floats && nchunk > 1) nchunk >>= 1;
    while (need(nsplit, nchunk) > ws_floats && nsplit > 1) nsplit >>= 1;

    float* kpart   = ws;
    float* dcsum   = kpart + (size_t)nsplit*196608;
    float* K2      = dcsum + 8;
    float* imgpart = K2 + 197632;

    switch (nsplit) {
      case 16: fwd_kernel<12><<<dim3(NVIEWS,16), 192, 0, stream>>>(x, points, kpart); break;
      case 8:  fwd_kernel<24><<<dim3(NVIEWS,8),  192, 0, stream>>>(x, points, kpart); break;
      case 4:  fwd_kernel<48><<<dim3(NVIEWS,4),  192, 0, stream>>>(x, points, kpart); break;
      case 2:  fwd_kernel<96><<<dim3(NVIEWS,2),  192, 0, stream>>>(x, points, kpart); break;
      default: fwd_kernel<192><<<dim3(NVIEWS,1), 192, 0, stream>>>(x, points, kpart); break;
    }
    dc_kernel<<<1, 256, 0, stream>>>(x, dcsum);
    combine_kernel<<<(NVIEWS*HALFT + 255)/256, 256, 0, stream>>>(
        kpart, dcsum, weights, K2, nsplit);
    switch (nchunk) {
      case 16: adj_kernel<8>  <<<dim3(NPIX/256,16), 256, 0, stream>>>(K2, points, imgpart); break;
      case 8:  adj_kernel<16> <<<dim3(NPIX/256,8),  256, 0, stream>>>(K2, points, imgpart); break;
      case 4:  adj_kernel<32> <<<dim3(NPIX/256,4),  256, 0, stream>>>(K2, points, imgpart); break;
      case 2:  adj_kernel<64> <<<dim3(NPIX/256,2),  256, 0, stream>>>(K2, points, imgpart); break;
      default: adj_kernel<128><<<dim3(NPIX/256,1),  256, 0, stream>>>(K2, points, imgpart); break;
    }
    out_fb_kernel<<<NPIX/256, 256, 0, stream>>>(imgpart, out, nchunk);
  }
}

// Round 6
// 148.034 us; speedup vs baseline: 9.0375x; 1.0726x over previous
//
#include <hip/hip_runtime.h>
#include <math.h>

// KSpaceResampling: type-2 NUDFT -> ramp weights -> type-1 adjoint -> abs
// R6: remove the 48us hipMemsetAsync(Am) — Am's pad rows feed only G pad
// columns which are never read (stage2 guards m2<M2); adj_gemm's pad K-columns
// are zeroed by tmat itself. Merge ygen+xgen into one launch.
// GEMM pipeline unchanged (validated R3/R4/R5).

#define HH 192
#define WW 192
#define NVIEWS 128
#define NSAMP 384
#define NPIX (HH*WW)      // 36864
#define HALFT 193         // stored t = 0..192
#define M2 12545          // 65 * 193  (v2 in [0,64])
#define M2P 12672         // padded
#define KTOT 25344        // 2 * M2P   (adjoint GEMM K: Cy-part ; Sy-part)
#define NSPLITK 33        // adjoint GEMM K-split (25344/33 = 768)

typedef __attribute__((ext_vector_type(8))) short bf16x8;
typedef __attribute__((ext_vector_type(4))) float f32x4;
typedef __attribute__((ext_vector_type(8))) unsigned short u16x8;

__device__ __forceinline__ void rot(float& cr, float& ci, float dr, float di) {
  float nr = cr*dr - ci*di;
  float ni = cr*di + ci*dr;
  cr = nr; ci = ni;
}
__device__ __forceinline__ unsigned short f2b(float f) {
  unsigned int u = __float_as_uint(f);
  u += 0x7fffu + ((u >> 16) & 1u);
  return (unsigned short)(u >> 16);
}
__device__ __forceinline__ float b2f(unsigned short h) {
  return __uint_as_float(((unsigned int)h) << 16);
}

// ---------------- phase tables (merged) ----------------
// blockIdx.y in [0,4): x-tables (h-splits): CxT/SxT/Am rows for hsplit=y
// blockIdx.y in [4,8): y-tables (w-splits): BT cols for wsplit=y-4
__global__ __launch_bounds__(256) void phase_kernel(
    const float* __restrict__ points, unsigned short* __restrict__ BT,
    unsigned short* __restrict__ CxT, unsigned short* __restrict__ SxT,
    unsigned short* __restrict__ Am) {
  const int v2 = blockIdx.x;
  const int role = blockIdx.y;
  const int t = threadIdx.x;
  if (t >= HALFT) return;
  if (role < 4) {
    const int hsplit = role;
    const float kx = points[(v2*NSAMP + t)*2 + 0];
    const int m2 = v2*HALFT + t;
    const int h0 = hsplit*48;
    float cr, ci; __sincosf(kx*(float)(h0-96), &ci, &cr);
    float dr, di; __sincosf(kx, &di, &dr);
    u16x8 pc, ps;
    for (int j = 0; j < 48; ++j) {
      const int h = h0 + j;
      CxT[(size_t)h*M2P + m2] = f2b(cr);
      SxT[(size_t)h*M2P + m2] = f2b(ci);
      pc[j&7] = f2b(cr); ps[j&7] = f2b(ci);
      if ((j&7) == 7) {
        *(u16x8*)(Am + (size_t)m2*192 + (h-7))         = pc;
        *(u16x8*)(Am + (size_t)(12672+m2)*192 + (h-7)) = ps;
      }
      rot(cr, ci, dr, di);
    }
  } else {
    const int wsplit = role - 4;
    const float ky = points[(v2*NSAMP + t)*2 + 1];
    const int kap = v2*HALFT + t;
    const int w0 = wsplit*48;
    float cr, ci; __sincosf(ky*(float)(w0-96), &ci, &cr);
    float dr, di; __sincosf(ky, &di, &dr);
    for (int j = 0; j < 48; ++j) {
      BT[(size_t)(w0+j)*KTOT + kap]       = f2b(cr);
      BT[(size_t)(w0+j)*KTOT + M2P + kap] = f2b(ci);
      rot(cr, ci, dr, di);
    }
  }
}

// ---------------- forward: gemm1 + stage2 ----------------

// XT[n=(cb*192+w)][h] = bf16(x[b][h][w][c]),  cb = b*2+c
__global__ __launch_bounds__(256) void xprep_kernel(
    const float* __restrict__ x, unsigned short* __restrict__ XT) {
  const int idx = blockIdx.x*256 + threadIdx.x;
  if (idx >= 768*192) return;
  const int n = idx / 192, h = idx - n*192;
  const int cb = n / 192, w = n - cb*192;
  const int b = cb >> 1, c = cb & 1;
  XT[idx] = f2b(x[(((size_t)b*HH + h)*WW + w)*2 + c]);
}

// G[n][m] = sum_h Am[m][h] * XT[n][h]   (bf16 out, fp32 accum)
// Am pad rows (m2 in [12545,12672) of each half) are NOT zeroed: the resulting
// G pad columns are never read (stage2 guards m2 < M2).
__global__ __launch_bounds__(256) void gemm1_kernel(
    const unsigned short* __restrict__ Am, const unsigned short* __restrict__ XT,
    unsigned short* __restrict__ G) {
  const int mt = blockIdx.x;          // 0..197
  const int nt = blockIdx.y;          // 0..3
  const int wv = threadIdx.x >> 6;
  const int lane = threadIdx.x & 63;
  const int r = lane & 15, kg = lane >> 4;
  const int mbase = mt*128 + (wv>>1)*64;
  const int nbase = nt*192 + (wv&1)*96;

  f32x4 acc[4][6];
  #pragma unroll
  for (int a = 0; a < 4; ++a)
    #pragma unroll
    for (int b = 0; b < 6; ++b) acc[a][b] = (f32x4){0.f,0.f,0.f,0.f};

  const unsigned short* Ap = Am + (size_t)(mbase + r)*192 + kg*8;
  const unsigned short* Bp = XT + (size_t)(nbase + r)*192 + kg*8;
  #pragma unroll
  for (int ks = 0; ks < 6; ++ks) {
    bf16x8 af[4], bfr[6];
    #pragma unroll
    for (int mf = 0; mf < 4; ++mf)
      af[mf] = *(const bf16x8*)(Ap + (size_t)mf*16*192 + ks*32);
    #pragma unroll
    for (int nf = 0; nf < 6; ++nf)
      bfr[nf] = *(const bf16x8*)(Bp + (size_t)nf*16*192 + ks*32);
    #pragma unroll
    for (int mf = 0; mf < 4; ++mf)
      #pragma unroll
      for (int nf = 0; nf < 6; ++nf)
        acc[mf][nf] = __builtin_amdgcn_mfma_f32_16x16x32_bf16(
            af[mf], bfr[nf], acc[mf][nf], 0, 0, 0);
  }
  #pragma unroll
  for (int mf = 0; mf < 4; ++mf)
    #pragma unroll
    for (int nf = 0; nf < 6; ++nf) {
      const int n = nbase + nf*16 + r;
      const int m = mbase + mf*16 + kg*4;
      ushort4 u = make_ushort4(f2b(acc[mf][nf][0]), f2b(acc[mf][nf][1]),
                               f2b(acc[mf][nf][2]), f2b(acc[mf][nf][3]));
      *(ushort4*)(G + (size_t)n*25344 + m) = u;
    }
}

// per m2: A1=sum_w Cr*Cy, A2=sum_w Si*Sy, A3=sum_w Si*Cy, A4=sum_w Cr*Sy
// combos: paired v2 in [1,63]: (2fA1, -2fA2, -2fA4, -2fA3); else (fkr,fkr,fki,fki)
// K2edge[v][d][cb][2] for t in {0,192}: weighted full-complex k per view.
__global__ __launch_bounds__(512) void stage2_kernel(
    const unsigned short* __restrict__ G, const float* __restrict__ points,
    const float* __restrict__ weights, float* __restrict__ combos,
    float* __restrict__ K2edge) {
  __shared__ float red[8][64][5];
  const int tid = threadIdx.x;
  const int wave = tid >> 6, lane = tid & 63;
  const int cb = wave >> 1, wh = wave & 1;
  const int m2 = blockIdx.x*64 + lane;
  const bool valid = (m2 < M2);
  float A1 = 0.f, A2 = 0.f, A3 = 0.f, A4 = 0.f;
  if (valid) {
    const int v2 = m2 / HALFT, t = m2 - v2*HALFT;
    const float ky = points[(v2*NSAMP + t)*2 + 1];
    const int w0 = wh*96;
    float cr, ci; __sincosf(ky*(float)(w0-96), &ci, &cr);
    float dr, di; __sincosf(ky, &di, &dr);
    const unsigned short* Gc = G + (size_t)(cb*192 + w0)*25344 + m2;
    const unsigned short* Gs = Gc + 12672;
    for (int w = 0; w < 96; ++w) {
      const float Cr = b2f(Gc[(size_t)w*25344]);
      const float Si = b2f(Gs[(size_t)w*25344]);
      A1 += Cr*cr; A4 += Cr*ci;
      A3 += Si*cr; A2 += Si*ci;
      rot(cr, ci, dr, di);
    }
  }
  red[wave][lane][0] = A1; red[wave][lane][1] = A2;
  red[wave][lane][2] = A3; red[wave][lane][3] = A4;
  __syncthreads();
  if (wh == 0 && valid) {
    A1 += red[wave+1][lane][0]; A2 += red[wave+1][lane][1];
    A3 += red[wave+1][lane][2]; A4 += red[wave+1][lane][3];
    const int v2 = m2 / HALFT, t = m2 - v2*HALFT;
    float f = weights[t] * (1.0f/36864.0f);
    if (t != 0 && t != 192) f *= 2.0f;
    const bool hp = (v2 >= 1 && v2 <= 63);
    float c0, c1, c2, c3;
    if (hp) {
      c0 =  2.f*f*A1; c1 = -2.f*f*A2; c2 = -2.f*f*A4; c3 = -2.f*f*A3;
    } else {
      const float kr = f*(A1 - A2), ki = -f*(A3 + A4);
      c0 = kr; c1 = kr; c2 = ki; c3 = ki;
    }
    combos[(cb*4+0)*M2P + m2] = c0;
    combos[(cb*4+1)*M2P + m2] = c1;
    combos[(cb*4+2)*M2P + m2] = c2;
    combos[(cb*4+3)*M2P + m2] = c3;
    if (t == 0 || t == 192) {
      const int d = (t == 0) ? 0 : 1;
      float* e = K2edge + ((v2*2 + d)*4 + cb)*2;
      e[0] = f*(A1 - A2); e[1] = -f*(A3 + A4);
      if (hp) {
        float* e2 = K2edge + (((128 - v2)*2 + d)*4 + cb)*2;
        e2[0] = f*(A1 + A2); e2[1] = f*(A3 - A4);
      }
    }
  }
}

// ---------------- adjoint (validated R3) ----------------

// A[j=(cb,h)][KTOT]: P = c0*cx - c3*sx ; Q = -(c1*sx + c2*cx)
__global__ __launch_bounds__(256) void tmat_kernel(
    const float* __restrict__ combos, const unsigned short* __restrict__ CxT,
    const unsigned short* __restrict__ SxT, unsigned short* __restrict__ A) {
  const int m2 = blockIdx.x*256 + threadIdx.x;
  if (m2 >= M2P) return;
  const int j = blockIdx.y;
  unsigned short* Arow = A + (size_t)j*KTOT;
  if (m2 >= M2) { Arow[m2] = 0; Arow[M2P + m2] = 0; return; }
  const int cb = j / 192, h = j - cb*192;
  const float cx = b2f(CxT[(size_t)h*M2P + m2]);
  const float sx = b2f(SxT[(size_t)h*M2P + m2]);
  const float c0 = combos[(cb*4+0)*M2P + m2];
  const float c1 = combos[(cb*4+1)*M2P + m2];
  const float c2 = combos[(cb*4+2)*M2P + m2];
  const float c3 = combos[(cb*4+3)*M2P + m2];
  Arow[m2]       = f2b(c0*cx - c3*sx);
  Arow[M2P + m2] = f2b(-(c1*sx + c2*cx));
}

__global__ __launch_bounds__(256) void adj_gemm(
    const unsigned short* __restrict__ A, const unsigned short* __restrict__ BT,
    float* __restrict__ partials) {
  const int mt = blockIdx.x;   // 0..5
  const int kc = blockIdx.y;   // 0..32
  const int wv = threadIdx.x >> 6;
  const int lane = threadIdx.x & 63;
  const int r = lane & 15, kg = lane >> 4;
  const int jbase = mt*128 + (wv>>1)*64;
  const int wbase = (wv&1)*96;
  const int kb = kc*768 + kg*8;

  f32x4 acc[4][6];
  #pragma unroll
  for (int a = 0; a < 4; ++a)
    #pragma unroll
    for (int b = 0; b < 6; ++b) acc[a][b] = (f32x4){0.f,0.f,0.f,0.f};

  const unsigned short* Ap = A + (size_t)(jbase + r)*KTOT + kb;
  const unsigned short* Bp = BT + (size_t)(wbase + r)*KTOT + kb;
  for (int ks = 0; ks < 24; ++ks) {
    bf16x8 af[4], bfr[6];
    #pragma unroll
    for (int mf = 0; mf < 4; ++mf)
      af[mf] = *(const bf16x8*)(Ap + (size_t)mf*16*KTOT + ks*32);
    #pragma unroll
    for (int nf = 0; nf < 6; ++nf)
      bfr[nf] = *(const bf16x8*)(Bp + (size_t)nf*16*KTOT + ks*32);
    #pragma unroll
    for (int mf = 0; mf < 4; ++mf)
      #pragma unroll
      for (int nf = 0; nf < 6; ++nf)
        acc[mf][nf] = __builtin_amdgcn_mfma_f32_16x16x32_bf16(
            af[mf], bfr[nf], acc[mf][nf], 0, 0, 0);
  }
  float* base = partials + (size_t)kc*192*768;
  #pragma unroll
  for (int mf = 0; mf < 4; ++mf)
    #pragma unroll
    for (int nf = 0; nf < 6; ++nf) {
      const int w = wbase + nf*16 + r;
      const int j = jbase + mf*16 + kg*4;
      *(f32x4*)(base + (size_t)w*768 + j) = acc[mf][nf];
    }
}

// imag part: ONLY t=0 samples contribute (t=192 DC is exactly real, phase 1).
// 8x8 pixel tiles, 4 view-groups of 32 per block, LDS reduce.
__global__ __launch_bounds__(256) void im_kernel(
    const unsigned short* __restrict__ BT, const unsigned short* __restrict__ CxT,
    const unsigned short* __restrict__ SxT, const float* __restrict__ K2edge,
    float* __restrict__ imb) {
  __shared__ float cxs[65][8], sxs[65][8], cys[65][8], sys[65][8];
  __shared__ float red[4][64][4];
  const int bx = blockIdx.x;            // 576 = 24x24 tiles of 8x8 pixels
  const int h0 = (bx/24)*8, w0 = (bx%24)*8;
  const int tid = threadIdx.x;
  for (int i = tid; i < 65*8; i += 256) {
    const int v2 = i >> 3, e = i & 7;
    const int kap = v2*HALFT;           // t = 0
    cxs[v2][e] = b2f(CxT[(size_t)(h0+e)*M2P + kap]);
    sxs[v2][e] = b2f(SxT[(size_t)(h0+e)*M2P + kap]);
    cys[v2][e] = b2f(BT[(size_t)(w0+e)*KTOT + kap]);
    sys[v2][e] = b2f(BT[(size_t)(w0+e)*KTOT + M2P + kap]);
  }
  __syncthreads();
  const int g = tid >> 6, hi = (tid >> 3) & 7, wi = tid & 7;
  float im[4] = {0,0,0,0};
  for (int v = g*32; v < g*32 + 32; ++v) {
    const int v2 = (v <= 64) ? v : 128 - v;
    const float sg = (v <= 64) ? 1.f : -1.f;
    const float cx = cxs[v2][hi], sx = sg*sxs[v2][hi];
    const float cy = cys[v2][wi], sy = sys[v2][wi];
    const float t1 = cx*sy + sx*cy;     // Im phase coeff of Kr
    const float t2 = cx*cy - sx*sy;     // Im phase coeff of Ki
    const int idx = v*16;               // (v*2 + d=0)*8
    #pragma unroll
    for (int cb = 0; cb < 4; ++cb)
      im[cb] += K2edge[idx + cb*2]*t1 + K2edge[idx + cb*2 + 1]*t2;
  }
  const int p = tid & 63;
  #pragma unroll
  for (int cb = 0; cb < 4; ++cb) red[g][p][cb] = im[cb];
  __syncthreads();
  if (g == 0) {
    #pragma unroll
    for (int cb = 0; cb < 4; ++cb)
      im[cb] += red[1][p][cb] + red[2][p][cb] + red[3][p][cb];
    const int pix = (h0+hi)*192 + (w0+wi);
    *(float4*)(imb + pix*4) = make_float4(im[0], im[1], im[2], im[3]);
  }
}

__global__ __launch_bounds__(256) void out_new_kernel(
    const float* __restrict__ partials, const float* __restrict__ imb,
    float* __restrict__ out) {
  const int g = blockIdx.x*256 + threadIdx.x;
  const int w = g / 768, cbh = g - w*768;
  const int cb = cbh / 192, h = cbh - cb*192;
  float re = 0.f;
  for (int kc = 0; kc < NSPLITK; ++kc)
    re += partials[(size_t)kc*147456 + g];
  const float im = imb[(h*192 + w)*4 + cb];
  const float mag = sqrtf(re*re + im*im);
  const int b = cb >> 1, c = cb & 1;
  out[((size_t)b*NPIX + h*192 + w)*2 + c] = mag;
}

// ---------------- fallback (r2, validated) ----------------

template <int HPER>
__global__ __launch_bounds__(192) void fwd_kernel(
    const float* __restrict__ x, const float* __restrict__ points,
    float* __restrict__ kpart) {
  const int v = blockIdx.x;
  const int split = blockIdx.y;
  const int t = threadIdx.x;
  const int m = v*NSAMP + t;
  const float kx = points[2*m+0];
  const float ky = points[2*m+1];
  const int h0 = split*HPER;

  float kr[4] = {0,0,0,0}, ki[4] = {0,0,0,0};
  float cyr, cyi; __sincosf(96.0f*ky, &cyi, &cyr);
  float dyr, dyi; __sincosf(-ky, &dyi, &dyr);
  float cx0r, cx0i; __sincosf(kx*(float)(96-h0), &cx0i, &cx0r);
  float dxr, dxi; __sincosf(-kx, &dxi, &dxr);

  for (int wp = 0; wp < 96; ++wp) {
    const int w0 = wp*2;
    float g0r[4]={0,0,0,0}, g0i[4]={0,0,0,0};
    float g1r[4]={0,0,0,0}, g1i[4]={0,0,0,0};
    float cxr = cx0r, cxi = cx0i;
    const float* p0 = x + (h0*WW + w0)*2;
    const float* p1 = p0 + HH*WW*2;
    #pragma unroll 4
    for (int h = 0; h < HPER; ++h) {
      float4 a = *(const float4*)(p0 + h*(WW*2));
      float4 b = *(const float4*)(p1 + h*(WW*2));
      g0r[0] += a.x*cxr; g0i[0] += a.x*cxi;
      g0r[1] += a.y*cxr; g0i[1] += a.y*cxi;
      g1r[0] += a.z*cxr; g1i[0] += a.z*cxi;
      g1r[1] += a.w*cxr; g1i[1] += a.w*cxi;
      g0r[2] += b.x*cxr; g0i[2] += b.x*cxi;
      g0r[3] += b.y*cxr; g0i[3] += b.y*cxi;
      g1r[2] += b.z*cxr; g1i[2] += b.z*cxi;
      g1r[3] += b.w*cxr; g1i[3] += b.w*cxi;
      rot(cxr, cxi, dxr, dxi);
    }
    #pragma unroll
    for (int cb = 0; cb < 4; ++cb) {
      kr[cb] += g0r[cb]*cyr - g0i[cb]*cyi;
      ki[cb] += g0r[cb]*cyi + g0i[cb]*cyr;
    }
    rot(cyr, cyi, dyr, dyi);
    #pragma unroll
    for (int cb = 0; cb < 4; ++cb) {
      kr[cb] += g1r[cb]*cyr - g1i[cb]*cyi;
      ki[cb] += g1r[cb]*cyi + g1i[cb]*cyr;
    }
    rot(cyr, cyi, dyr, dyi);
  }
  float* o = kpart + (((split*NVIEWS + v)*192 + t)*4)*2;
  #pragma unroll
  for (int cb = 0; cb < 4; ++cb) { o[2*cb] = kr[cb]; o[2*cb+1] = ki[cb]; }
}

__global__ __launch_bounds__(256) void dc_kernel(
    const float* __restrict__ x, float* __restrict__ dcsum) {
  const int tid = threadIdx.x;
  float s0=0.f, s1=0.f, s2=0.f, s3=0.f;
  for (int i = tid; i < NPIX; i += 256) {
    float2 a = *(const float2*)(x + i*2);
    float2 b = *(const float2*)(x + HH*WW*2 + i*2);
    s0 += a.x; s1 += a.y; s2 += b.x; s3 += b.y;
  }
  #pragma unroll
  for (int off = 32; off > 0; off >>= 1) {
    s0 += __shfl_down(s0, off);
    s1 += __shfl_down(s1, off);
    s2 += __shfl_down(s2, off);
    s3 += __shfl_down(s3, off);
  }
  __shared__ float red[4][4];
  const int wv = tid >> 6, ln = tid & 63;
  if (ln == 0) { red[0][wv]=s0; red[1][wv]=s1; red[2][wv]=s2; red[3][wv]=s3; }
  __syncthreads();
  if (tid < 4) {
    float tot = red[tid][0]+red[tid][1]+red[tid][2]+red[tid][3];
    dcsum[2*tid] = tot; dcsum[2*tid+1] = 0.0f;
  }
}

__global__ __launch_bounds__(256) void combine_kernel(
    const float* __restrict__ kpart, const float* __restrict__ dcsum,
    const float* __restrict__ weights, float* __restrict__ K2, int nsplit) {
  const int idx = blockIdx.x*256 + threadIdx.x;
  if (idx >= NVIEWS*HALFT) return;
  const int v = idx / HALFT, t = idx % HALFT;
  float f = weights[t] * (1.0f/36864.0f);
  if (t != 0 && t != 192) f *= 2.0f;
  float o[8];
  if (t == 192) {
    #pragma unroll
    for (int cb = 0; cb < 4; ++cb) { o[2*cb] = f*dcsum[2*cb]; o[2*cb+1] = f*dcsum[2*cb+1]; }
  } else {
    #pragma unroll
    for (int cb = 0; cb < 4; ++cb) {
      float ar = 0.f, ai = 0.f;
      for (int s = 0; s < nsplit; ++s) {
        const float* p = kpart + (((s*NVIEWS + v)*192 + t)*4 + cb)*2;
        ar += p[0]; ai += p[1];
      }
      o[2*cb] = f*ar; o[2*cb+1] = f*ai;
    }
  }
  float* q = K2 + idx*8;
  #pragma unroll
  for (int j = 0; j < 8; ++j) q[j] = o[j];
}

template <int VPC>
__global__ __launch_bounds__(256) void adj_kernel(
    const float* __restrict__ K2, const float* __restrict__ points,
    float* __restrict__ imgpart) {
  const int pix = blockIdx.x*256 + threadIdx.x;
  const int chunk = blockIdx.y;
  const float nh = (float)(pix / WW - 96);
  const float nw = (float)(pix % WW - 96);
  float re[4] = {0,0,0,0}, im[4] = {0,0,0,0};
  const float INVPI = 0.3183098861837907f;
  const float PI192 = 3.14159265358979f / 192.0f;
  for (int v = chunk*VPC; v < chunk*VPC + VPC; ++v) {
    const float ct = -points[2*(v*NSAMP)+0] * INVPI;
    const float st = -points[2*(v*NSAMP)+1] * INVPI;
    const float alpha = ct*nh + st*nw;
    const float delta = alpha * PI192;
    float dr, di; __sincosf(delta, &di, &dr);
    float c0r, c0i; __sincosf(-192.0f*delta, &c0i, &c0r);
    const float* Kv = K2 + v*HALFT*8;
    #pragma unroll
    for (int cb = 0; cb < 4; ++cb) {
      float a = Kv[2*cb], b = Kv[2*cb+1];
      re[cb] += a*c0r - b*c0i;
      im[cb] += a*c0i + b*c0r;
    }
    float d2r = dr*dr - di*di, d2i = 2.0f*dr*di;
    float ar = c0r*dr - c0i*di, ai = c0r*di + c0i*dr;
    float br = ar*dr - ai*di,  bi = ar*di + ai*dr;
    for (int i = 0; i < 95; ++i) {
      const float* ka = Kv + (2*i+1)*8;
      const float* kb = Kv + (2*i+2)*8;
      #pragma unroll
      for (int cb = 0; cb < 4; ++cb)
        re[cb] += ka[2*cb]*ar - ka[2*cb+1]*ai;
      #pragma unroll
      for (int cb = 0; cb < 4; ++cb)
        re[cb] += kb[2*cb]*br - kb[2*cb+1]*bi;
      rot(ar, ai, d2r, d2i);
      rot(br, bi, d2r, d2i);
    }
    {
      const float* ka = Kv + 191*8;
      #pragma unroll
      for (int cb = 0; cb < 4; ++cb)
        re[cb] += ka[2*cb]*ar - ka[2*cb+1]*ai;
    }
    const float* kd = Kv + 192*8;
    #pragma unroll
    for (int cb = 0; cb < 4; ++cb) { re[cb] += kd[2*cb]; im[cb] += kd[2*cb+1]; }
  }
  float* o = imgpart + (chunk*NPIX + pix)*8;
  #pragma unroll
  for (int cb = 0; cb < 4; ++cb) { o[2*cb] = re[cb]; o[2*cb+1] = im[cb]; }
}

__global__ __launch_bounds__(256) void out_fb_kernel(
    const float* __restrict__ imgpart, float* __restrict__ out, int nchunk) {
  const int pix = blockIdx.x*256 + threadIdx.x;
  float re[4] = {0,0,0,0}, im[4] = {0,0,0,0};
  for (int ch = 0; ch < nchunk; ++ch) {
    const float* p = imgpart + (ch*NPIX + pix)*8;
    #pragma unroll
    for (int cb = 0; cb < 4; ++cb) { re[cb] += p[2*cb]; im[cb] += p[2*cb+1]; }
  }
  #pragma unroll
  for (int b = 0; b < 2; ++b)
    #pragma unroll
    for (int c = 0; c < 2; ++c) {
      const int cb = b*2 + c;
      out[(b*NPIX + pix)*2 + c] = sqrtf(re[cb]*re[cb] + im[cb]*im[cb]);
    }
}

extern "C" void kernel_launch(void* const* d_in, const int* in_sizes, int n_in,
                              void* d_out, int out_size, void* d_ws, size_t ws_size,
                              hipStream_t stream) {
  const float* x       = (const float*)d_in[0];
  const float* points  = (const float*)d_in[1];
  const float* weights = (const float*)d_in[2];
  float* out = (float*)d_out;

  const size_t NEED = 79265792ull;
  if (ws_size >= NEED) {
    char* wsb = (char*)d_ws;
    unsigned short* BT   = (unsigned short*)(wsb + 0);          //  9,732,096
    unsigned short* CxT  = (unsigned short*)(wsb + 9732096);    //  4,866,048
    unsigned short* SxT  = (unsigned short*)(wsb + 14598144);   //  4,866,048
    float* combos        = (float*)(wsb + 19464192);            //    811,008
    float* K2edge        = (float*)(wsb + 20275200);            //      8,192
    char* S              = wsb + 20283392;                      // 58,982,400
    // phase A
    unsigned short* Am   = (unsigned short*)(S + 0);            //  9,732,096
    unsigned short* XT   = (unsigned short*)(S + 9732096);      //    294,912
    unsigned short* G    = (unsigned short*)(S + 10027008);     // 38,928,384
    // phase B (overlaps phase A; stream-ordered)
    unsigned short* Aadj = (unsigned short*)(S + 0);            // 38,928,384
    float* partials      = (float*)(S + 38928384);              // 19,464,192
    float* imb           = (float*)(S + 58392576);              //    589,824

    phase_kernel<<<dim3(65,8), 256, 0, stream>>>(points, BT, CxT, SxT, Am);
    xprep_kernel<<<576, 256, 0, stream>>>(x, XT);
    gemm1_kernel<<<dim3(198,4), 256, 0, stream>>>(Am, XT, G);
    stage2_kernel<<<198, 512, 0, stream>>>(G, points, weights, combos, K2edge);
    tmat_kernel<<<dim3((M2P + 255)/256, 768), 256, 0, stream>>>(
        combos, CxT, SxT, Aadj);
    adj_gemm<<<dim3(6, NSPLITK), 256, 0, stream>>>(Aadj, BT, partials);
    im_kernel<<<576, 256, 0, stream>>>(BT, CxT, SxT, K2edge, imb);
    out_new_kernel<<<(192*768)/256, 256, 0, stream>>>(partials, imb, out);
  } else {
    // r2 fallback path
    float* ws = (float*)d_ws;
    const size_t ws_floats = ws_size / sizeof(float);
    int nsplit = 16, nchunk = 16;
    auto need = [&](int ns, int nc) -> size_t {
      return (size_t)ns*196608 + 8 + 197632 + (size_t)nc*294912;
    };
    while (need(nsplit, nchunk) > ws_floats && nchunk > 1) nchunk >>= 1;
    while (need(nsplit, nchunk) > ws_floats && nsplit > 1) nsplit >>= 1;

    float* kpart   = ws;
    float* dcsum   = kpart + (size_t)nsplit*196608;
    float* K2      = dcsum + 8;
    float* imgpart = K2 + 197632;

    switch (nsplit) {
      case 16: fwd_kernel<12><<<dim3(NVIEWS,16), 192, 0, stream>>>(x, points, kpart); break;
      case 8:  fwd_kernel<24><<<dim3(NVIEWS,8),  192, 0, stream>>>(x, points, kpart); break;
      case 4:  fwd_kernel<48><<<dim3(NVIEWS,4),  192, 0, stream>>>(x, points, kpart); break;
      case 2:  fwd_kernel<96><<<dim3(NVIEWS,2),  192, 0, stream>>>(x, points, kpart); break;
      default: fwd_kernel<192><<<dim3(NVIEWS,1), 192, 0, stream>>>(x, points, kpart); break;
    }
    dc_kernel<<<1, 256, 0, stream>>>(x, dcsum);
    combine_kernel<<<(NVIEWS*HALFT + 255)/256, 256, 0, stream>>>(
        kpart, dcsum, weights, K2, nsplit);
    switch (nchunk) {
      case 16: adj_kernel<8>  <<<dim3(NPIX/256,16), 256, 0, stream>>>(K2, points, imgpart); break;
      case 8:  adj_kernel<16> <<<dim3(NPIX/256,8),  256, 0, stream>>>(K2, points, imgpart); break;
      case 4:  adj_kernel<32> <<<dim3(NPIX/256,4),  256, 0, stream>>>(K2, points, imgpart); break;
      case 2:  adj_kernel<64> <<<dim3(NPIX/256,2),  256, 0, stream>>>(K2, points, imgpart); break;
      default: adj_kernel<128><<<dim3(NPIX/256,1),  256, 0, stream>>>(K2, points, imgpart); break;
    }
    out_fb_kernel<<<NPIX/256, 256, 0, stream>>>(imgpart, out, nchunk);
  }
}

// Round 7
// 137.301 us; speedup vs baseline: 9.7440x; 1.0782x over previous
//
#include <hip/hip_runtime.h>
#include <math.h>

// KSpaceResampling: type-2 NUDFT -> ramp weights -> type-1 adjoint -> abs
// R7: fuse stage2 into gemm1 — apply the w-phase contraction to the MFMA
// accumulator in-register (sincos + shfl_xor col-reduce + LDS wave-combine),
// writing 0.8MB Abuf instead of the 39MB G scatter (+39MB re-read).
// stage2 replaced by tiny combine2. Everything else validated R3-R6.

#define HH 192
#define WW 192
#define NVIEWS 128
#define NSAMP 384
#define NPIX (HH*WW)      // 36864
#define HALFT 193         // stored t = 0..192
#define M2 12545          // 65 * 193  (v2 in [0,64])
#define M2P 12672         // padded
#define KTOT 25344        // 2 * M2P   (adjoint GEMM K: Cy-part ; Sy-part)
#define NSPLITK 33        // adjoint GEMM K-split (25344/33 = 768)

typedef __attribute__((ext_vector_type(8))) short bf16x8;
typedef __attribute__((ext_vector_type(4))) float f32x4;
typedef __attribute__((ext_vector_type(8))) unsigned short u16x8;

__device__ __forceinline__ void rot(float& cr, float& ci, float dr, float di) {
  float nr = cr*dr - ci*di;
  float ni = cr*di + ci*dr;
  cr = nr; ci = ni;
}
__device__ __forceinline__ unsigned short f2b(float f) {
  unsigned int u = __float_as_uint(f);
  u += 0x7fffu + ((u >> 16) & 1u);
  return (unsigned short)(u >> 16);
}
__device__ __forceinline__ float b2f(unsigned short h) {
  return __uint_as_float(((unsigned int)h) << 16);
}

// ---------------- phase tables (merged) ----------------
// blockIdx.y in [0,4): x-tables (h-splits): CxT/SxT/Am rows for hsplit=y
// blockIdx.y in [4,8): y-tables (w-splits): BT cols for wsplit=y-4
__global__ __launch_bounds__(256) void phase_kernel(
    const float* __restrict__ points, unsigned short* __restrict__ BT,
    unsigned short* __restrict__ CxT, unsigned short* __restrict__ SxT,
    unsigned short* __restrict__ Am) {
  const int v2 = blockIdx.x;
  const int role = blockIdx.y;
  const int t = threadIdx.x;
  if (t >= HALFT) return;
  if (role < 4) {
    const int hsplit = role;
    const float kx = points[(v2*NSAMP + t)*2 + 0];
    const int m2 = v2*HALFT + t;
    const int h0 = hsplit*48;
    float cr, ci; __sincosf(kx*(float)(h0-96), &ci, &cr);
    float dr, di; __sincosf(kx, &di, &dr);
    u16x8 pc, ps;
    for (int j = 0; j < 48; ++j) {
      const int h = h0 + j;
      CxT[(size_t)h*M2P + m2] = f2b(cr);
      SxT[(size_t)h*M2P + m2] = f2b(ci);
      pc[j&7] = f2b(cr); ps[j&7] = f2b(ci);
      if ((j&7) == 7) {
        *(u16x8*)(Am + (size_t)m2*192 + (h-7))         = pc;
        *(u16x8*)(Am + (size_t)(12672+m2)*192 + (h-7)) = ps;
      }
      rot(cr, ci, dr, di);
    }
  } else {
    const int wsplit = role - 4;
    const float ky = points[(v2*NSAMP + t)*2 + 1];
    const int kap = v2*HALFT + t;
    const int w0 = wsplit*48;
    float cr, ci; __sincosf(ky*(float)(w0-96), &ci, &cr);
    float dr, di; __sincosf(ky, &di, &dr);
    for (int j = 0; j < 48; ++j) {
      BT[(size_t)(w0+j)*KTOT + kap]       = f2b(cr);
      BT[(size_t)(w0+j)*KTOT + M2P + kap] = f2b(ci);
      rot(cr, ci, dr, di);
    }
  }
}

// ---------------- forward: fused gemm1 (+ w-phase contraction) ----------------

// XT[n=(cb*192+w)][h] = bf16(x[b][h][w][c]),  cb = b*2+c
__global__ __launch_bounds__(256) void xprep_kernel(
    const float* __restrict__ x, unsigned short* __restrict__ XT) {
  const int idx = blockIdx.x*256 + threadIdx.x;
  if (idx >= 768*192) return;
  const int n = idx / 192, h = idx - n*192;
  const int cb = n / 192, w = n - cb*192;
  const int b = cb >> 1, c = cb & 1;
  XT[idx] = f2b(x[(((size_t)b*HH + h)*WW + w)*2 + c]);
}

// Block (mt, cb): computes the G tile [m 128][w 192] in registers (MFMA over
// h), then contracts over w with phases cis(ky[m]*(w-96)) in-register:
//   Cx blocks (mt<99):  A1 = sum_w G*cos, A4 = sum_w G*sin
//   Sx blocks (mt>=99): A3 = sum_w G*cos, A2 = sum_w G*sin
// shfl_xor reduces the 16-lane col group, LDS combines the two w-half waves.
// Writes Abuf[cb][m2][{0:A1,1:A2,2:A3,3:A4}] (disjoint slots, no atomics).
__global__ __launch_bounds__(256) void gemm1_kernel(
    const unsigned short* __restrict__ Am, const unsigned short* __restrict__ XT,
    const float* __restrict__ points, float* __restrict__ Abuf) {
  __shared__ float lds[2][128][2];
  const int mt = blockIdx.x;          // 0..197
  const int cb = blockIdx.y;          // 0..3
  const int wv = threadIdx.x >> 6;
  const int lane = threadIdx.x & 63;
  const int r = lane & 15, kg = lane >> 4;
  const int mhalf = wv >> 1;          // 0/1: m 64-half
  const int whalf = wv & 1;           // 0/1: w 96-half
  const int mbase = mt*128 + mhalf*64;
  const int wbase = whalf*96;
  const int nbase = cb*192 + wbase;

  f32x4 acc[4][6];
  #pragma unroll
  for (int a = 0; a < 4; ++a)
    #pragma unroll
    for (int b = 0; b < 6; ++b) acc[a][b] = (f32x4){0.f,0.f,0.f,0.f};

  const unsigned short* Ap = Am + (size_t)(mbase + r)*192 + kg*8;
  const unsigned short* Bp = XT + (size_t)(nbase + r)*192 + kg*8;
  #pragma unroll
  for (int ks = 0; ks < 6; ++ks) {
    bf16x8 af[4], bfr[6];
    #pragma unroll
    for (int mf = 0; mf < 4; ++mf)
      af[mf] = *(const bf16x8*)(Ap + (size_t)mf*16*192 + ks*32);
    #pragma unroll
    for (int nf = 0; nf < 6; ++nf)
      bfr[nf] = *(const bf16x8*)(Bp + (size_t)nf*16*192 + ks*32);
    #pragma unroll
    for (int mf = 0; mf < 4; ++mf)
      #pragma unroll
      for (int nf = 0; nf < 6; ++nf)
        acc[mf][nf] = __builtin_amdgcn_mfma_f32_16x16x32_bf16(
            af[mf], bfr[nf], acc[mf][nf], 0, 0, 0);
  }

  // in-register phase contraction over w
  const bool isCx = (mt < 99);
  const int m2w = mbase - (isCx ? 0 : 12672);
  float accA[16], accB[16];
  #pragma unroll
  for (int mf = 0; mf < 4; ++mf)
    #pragma unroll
    for (int reg = 0; reg < 4; ++reg) {
      const int m2 = m2w + mf*16 + kg*4 + reg;
      const int v2 = m2 / HALFT, t = m2 - v2*HALFT;
      const float ky = points[(v2*NSAMP + t)*2 + 1];   // safe: v2<=65 < 128
      float a0 = 0.f, b0 = 0.f;
      #pragma unroll
      for (int nf = 0; nf < 6; ++nf) {
        const float wo = (float)(wbase + nf*16 + r - 96);
        float sy, cy; __sincosf(ky*wo, &sy, &cy);
        const float g = acc[mf][nf][reg];
        a0 = fmaf(g, cy, a0);
        b0 = fmaf(g, sy, b0);
      }
      accA[mf*4+reg] = a0; accB[mf*4+reg] = b0;
    }
  // reduce over the 16-lane col group (w index r)
  #pragma unroll
  for (int msk = 1; msk <= 8; msk <<= 1) {
    #pragma unroll
    for (int i = 0; i < 16; ++i) {
      accA[i] += __shfl_xor(accA[i], msk);
      accB[i] += __shfl_xor(accB[i], msk);
    }
  }
  if (r == 0) {
    #pragma unroll
    for (int mf = 0; mf < 4; ++mf)
      #pragma unroll
      for (int reg = 0; reg < 4; ++reg) {
        const int mloc = mhalf*64 + mf*16 + kg*4 + reg;
        lds[whalf][mloc][0] = accA[mf*4+reg];
        lds[whalf][mloc][1] = accB[mf*4+reg];
      }
  }
  __syncthreads();
  {
    const int tid = threadIdx.x;
    const int mloc = tid >> 1, slot = tid & 1;
    const float val = lds[0][mloc][slot] + lds[1][mloc][slot];
    const int m2 = mt*128 + mloc - (isCx ? 0 : 12672);
    // Cx: slot0->A1(0), slot1->A4(3); Sx: slot0->A3(2), slot1->A2(1)
    const int idx = isCx ? (slot ? 3 : 0) : (slot ? 1 : 2);
    Abuf[((size_t)cb*M2P + m2)*4 + idx] = val;
  }
}

// Abuf -> combos + K2edge (same algebra as the validated stage2 tail)
__global__ __launch_bounds__(256) void combine2_kernel(
    const float* __restrict__ Abuf, const float* __restrict__ weights,
    float* __restrict__ combos, float* __restrict__ K2edge) {
  const int m2 = blockIdx.x*256 + threadIdx.x;
  if (m2 >= M2) return;
  const int v2 = m2 / HALFT, t = m2 - v2*HALFT;
  float f = weights[t] * (1.0f/36864.0f);
  if (t != 0 && t != 192) f *= 2.0f;
  const bool hp = (v2 >= 1 && v2 <= 63);
  #pragma unroll
  for (int cb = 0; cb < 4; ++cb) {
    const float4 A = *(const float4*)(Abuf + ((size_t)cb*M2P + m2)*4);
    const float A1 = A.x, A2 = A.y, A3 = A.z, A4 = A.w;
    float c0, c1, c2, c3;
    if (hp) {
      c0 =  2.f*f*A1; c1 = -2.f*f*A2; c2 = -2.f*f*A4; c3 = -2.f*f*A3;
    } else {
      const float kr = f*(A1 - A2), ki = -f*(A3 + A4);
      c0 = kr; c1 = kr; c2 = ki; c3 = ki;
    }
    combos[(cb*4+0)*M2P + m2] = c0;
    combos[(cb*4+1)*M2P + m2] = c1;
    combos[(cb*4+2)*M2P + m2] = c2;
    combos[(cb*4+3)*M2P + m2] = c3;
    if (t == 0 || t == 192) {
      const int d = (t == 0) ? 0 : 1;
      float* e = K2edge + ((v2*2 + d)*4 + cb)*2;
      e[0] = f*(A1 - A2); e[1] = -f*(A3 + A4);
      if (hp) {
        float* e2 = K2edge + (((128 - v2)*2 + d)*4 + cb)*2;
        e2[0] = f*(A1 + A2); e2[1] = f*(A3 - A4);
      }
    }
  }
}

// ---------------- adjoint (validated R3) ----------------

// A[j=(cb,h)][KTOT]: P = c0*cx - c3*sx ; Q = -(c1*sx + c2*cx)
__global__ __launch_bounds__(256) void tmat_kernel(
    const float* __restrict__ combos, const unsigned short* __restrict__ CxT,
    const unsigned short* __restrict__ SxT, unsigned short* __restrict__ A) {
  const int m2 = blockIdx.x*256 + threadIdx.x;
  if (m2 >= M2P) return;
  const int j = blockIdx.y;
  unsigned short* Arow = A + (size_t)j*KTOT;
  if (m2 >= M2) { Arow[m2] = 0; Arow[M2P + m2] = 0; return; }
  const int cb = j / 192, h = j - cb*192;
  const float cx = b2f(CxT[(size_t)h*M2P + m2]);
  const float sx = b2f(SxT[(size_t)h*M2P + m2]);
  const float c0 = combos[(cb*4+0)*M2P + m2];
  const float c1 = combos[(cb*4+1)*M2P + m2];
  const float c2 = combos[(cb*4+2)*M2P + m2];
  const float c3 = combos[(cb*4+3)*M2P + m2];
  Arow[m2]       = f2b(c0*cx - c3*sx);
  Arow[M2P + m2] = f2b(-(c1*sx + c2*cx));
}

__global__ __launch_bounds__(256) void adj_gemm(
    const unsigned short* __restrict__ A, const unsigned short* __restrict__ BT,
    float* __restrict__ partials) {
  const int mt = blockIdx.x;   // 0..5
  const int kc = blockIdx.y;   // 0..32
  const int wv = threadIdx.x >> 6;
  const int lane = threadIdx.x & 63;
  const int r = lane & 15, kg = lane >> 4;
  const int jbase = mt*128 + (wv>>1)*64;
  const int wbase = (wv&1)*96;
  const int kb = kc*768 + kg*8;

  f32x4 acc[4][6];
  #pragma unroll
  for (int a = 0; a < 4; ++a)
    #pragma unroll
    for (int b = 0; b < 6; ++b) acc[a][b] = (f32x4){0.f,0.f,0.f,0.f};

  const unsigned short* Ap = A + (size_t)(jbase + r)*KTOT + kb;
  const unsigned short* Bp = BT + (size_t)(wbase + r)*KTOT + kb;
  for (int ks = 0; ks < 24; ++ks) {
    bf16x8 af[4], bfr[6];
    #pragma unroll
    for (int mf = 0; mf < 4; ++mf)
      af[mf] = *(const bf16x8*)(Ap + (size_t)mf*16*KTOT + ks*32);
    #pragma unroll
    for (int nf = 0; nf < 6; ++nf)
      bfr[nf] = *(const bf16x8*)(Bp + (size_t)nf*16*KTOT + ks*32);
    #pragma unroll
    for (int mf = 0; mf < 4; ++mf)
      #pragma unroll
      for (int nf = 0; nf < 6; ++nf)
        acc[mf][nf] = __builtin_amdgcn_mfma_f32_16x16x32_bf16(
            af[mf], bfr[nf], acc[mf][nf], 0, 0, 0);
  }
  float* base = partials + (size_t)kc*192*768;
  #pragma unroll
  for (int mf = 0; mf < 4; ++mf)
    #pragma unroll
    for (int nf = 0; nf < 6; ++nf) {
      const int w = wbase + nf*16 + r;
      const int j = jbase + mf*16 + kg*4;
      *(f32x4*)(base + (size_t)w*768 + j) = acc[mf][nf];
    }
}

// imag part: ONLY t=0 samples contribute (t=192 DC is exactly real, phase 1).
// 8x8 pixel tiles, 4 view-groups of 32 per block, LDS reduce.
__global__ __launch_bounds__(256) void im_kernel(
    const unsigned short* __restrict__ BT, const unsigned short* __restrict__ CxT,
    const unsigned short* __restrict__ SxT, const float* __restrict__ K2edge,
    float* __restrict__ imb) {
  __shared__ float cxs[65][8], sxs[65][8], cys[65][8], sys[65][8];
  __shared__ float red[4][64][4];
  const int bx = blockIdx.x;            // 576 = 24x24 tiles of 8x8 pixels
  const int h0 = (bx/24)*8, w0 = (bx%24)*8;
  const int tid = threadIdx.x;
  for (int i = tid; i < 65*8; i += 256) {
    const int v2 = i >> 3, e = i & 7;
    const int kap = v2*HALFT;           // t = 0
    cxs[v2][e] = b2f(CxT[(size_t)(h0+e)*M2P + kap]);
    sxs[v2][e] = b2f(SxT[(size_t)(h0+e)*M2P + kap]);
    cys[v2][e] = b2f(BT[(size_t)(w0+e)*KTOT + kap]);
    sys[v2][e] = b2f(BT[(size_t)(w0+e)*KTOT + M2P + kap]);
  }
  __syncthreads();
  const int g = tid >> 6, hi = (tid >> 3) & 7, wi = tid & 7;
  float im[4] = {0,0,0,0};
  for (int v = g*32; v < g*32 + 32; ++v) {
    const int v2 = (v <= 64) ? v : 128 - v;
    const float sg = (v <= 64) ? 1.f : -1.f;
    const float cx = cxs[v2][hi], sx = sg*sxs[v2][hi];
    const float cy = cys[v2][wi], sy = sys[v2][wi];
    const float t1 = cx*sy + sx*cy;     // Im phase coeff of Kr
    const float t2 = cx*cy - sx*sy;     // Im phase coeff of Ki
    const int idx = v*16;               // (v*2 + d=0)*8
    #pragma unroll
    for (int cb = 0; cb < 4; ++cb)
      im[cb] += K2edge[idx + cb*2]*t1 + K2edge[idx + cb*2 + 1]*t2;
  }
  const int p = tid & 63;
  #pragma unroll
  for (int cb = 0; cb < 4; ++cb) red[g][p][cb] = im[cb];
  __syncthreads();
  if (g == 0) {
    #pragma unroll
    for (int cb = 0; cb < 4; ++cb)
      im[cb] += red[1][p][cb] + red[2][p][cb] + red[3][p][cb];
    const int pix = (h0+hi)*192 + (w0+wi);
    *(float4*)(imb + pix*4) = make_float4(im[0], im[1], im[2], im[3]);
  }
}

__global__ __launch_bounds__(256) void out_new_kernel(
    const float* __restrict__ partials, const float* __restrict__ imb,
    float* __restrict__ out) {
  const int g = blockIdx.x*256 + threadIdx.x;
  const int w = g / 768, cbh = g - w*768;
  const int cb = cbh / 192, h = cbh - cb*192;
  float re = 0.f;
  for (int kc = 0; kc < NSPLITK; ++kc)
    re += partials[(size_t)kc*147456 + g];
  const float im = imb[(h*192 + w)*4 + cb];
  const float mag = sqrtf(re*re + im*im);
  const int b = cb >> 1, c = cb & 1;
  out[((size_t)b*NPIX + h*192 + w)*2 + c] = mag;
}

// ---------------- fallback (r2, validated) ----------------

template <int HPER>
__global__ __launch_bounds__(192) void fwd_kernel(
    const float* __restrict__ x, const float* __restrict__ points,
    float* __restrict__ kpart) {
  const int v = blockIdx.x;
  const int split = blockIdx.y;
  const int t = threadIdx.x;
  const int m = v*NSAMP + t;
  const float kx = points[2*m+0];
  const float ky = points[2*m+1];
  const int h0 = split*HPER;

  float kr[4] = {0,0,0,0}, ki[4] = {0,0,0,0};
  float cyr, cyi; __sincosf(96.0f*ky, &cyi, &cyr);
  float dyr, dyi; __sincosf(-ky, &dyi, &dyr);
  float cx0r, cx0i; __sincosf(kx*(float)(96-h0), &cx0i, &cx0r);
  float dxr, dxi; __sincosf(-kx, &dxi, &dxr);

  for (int wp = 0; wp < 96; ++wp) {
    const int w0 = wp*2;
    float g0r[4]={0,0,0,0}, g0i[4]={0,0,0,0};
    float g1r[4]={0,0,0,0}, g1i[4]={0,0,0,0};
    float cxr = cx0r, cxi = cx0i;
    const float* p0 = x + (h0*WW + w0)*2;
    const float* p1 = p0 + HH*WW*2;
    #pragma unroll 4
    for (int h = 0; h < HPER; ++h) {
      float4 a = *(const float4*)(p0 + h*(WW*2));
      float4 b = *(const float4*)(p1 + h*(WW*2));
      g0r[0] += a.x*cxr; g0i[0] += a.x*cxi;
      g0r[1] += a.y*cxr; g0i[1] += a.y*cxi;
      g1r[0] += a.z*cxr; g1i[0] += a.z*cxi;
      g1r[1] += a.w*cxr; g1i[1] += a.w*cxi;
      g0r[2] += b.x*cxr; g0i[2] += b.x*cxi;
      g0r[3] += b.y*cxr; g0i[3] += b.y*cxi;
      g1r[2] += b.z*cxr; g1i[2] += b.z*cxi;
      g1r[3] += b.w*cxr; g1i[3] += b.w*cxi;
      rot(cxr, cxi, dxr, dxi);
    }
    #pragma unroll
    for (int cb = 0; cb < 4; ++cb) {
      kr[cb] += g0r[cb]*cyr - g0i[cb]*cyi;
      ki[cb] += g0r[cb]*cyi + g0i[cb]*cyr;
    }
    rot(cyr, cyi, dyr, dyi);
    #pragma unroll
    for (int cb = 0; cb < 4; ++cb) {
      kr[cb] += g1r[cb]*cyr - g1i[cb]*cyi;
      ki[cb] += g1r[cb]*cyi + g1i[cb]*cyr;
    }
    rot(cyr, cyi, dyr, dyi);
  }
  float* o = kpart + (((split*NVIEWS + v)*192 + t)*4)*2;
  #pragma unroll
  for (int cb = 0; cb < 4; ++cb) { o[2*cb] = kr[cb]; o[2*cb+1] = ki[cb]; }
}

__global__ __launch_bounds__(256) void dc_kernel(
    const float* __restrict__ x, float* __restrict__ dcsum) {
  const int tid = threadIdx.x;
  float s0=0.f, s1=0.f, s2=0.f, s3=0.f;
  for (int i = tid; i < NPIX; i += 256) {
    float2 a = *(const float2*)(x + i*2);
    float2 b = *(const float2*)(x + HH*WW*2 + i*2);
    s0 += a.x; s1 += a.y; s2 += b.x; s3 += b.y;
  }
  #pragma unroll
  for (int off = 32; off > 0; off >>= 1) {
    s0 += __shfl_down(s0, off);
    s1 += __shfl_down(s1, off);
    s2 += __shfl_down(s2, off);
    s3 += __shfl_down(s3, off);
  }
  __shared__ float red[4][4];
  const int wv = tid >> 6, ln = tid & 63;
  if (ln == 0) { red[0][wv]=s0; red[1][wv]=s1; red[2][wv]=s2; red[3][wv]=s3; }
  __syncthreads();
  if (tid < 4) {
    float tot = red[tid][0]+red[tid][1]+red[tid][2]+red[tid][3];
    dcsum[2*tid] = tot; dcsum[2*tid+1] = 0.0f;
  }
}

__global__ __launch_bounds__(256) void combine_kernel(
    const float* __restrict__ kpart, const float* __restrict__ dcsum,
    const float* __restrict__ weights, float* __restrict__ K2, int nsplit) {
  const int idx = blockIdx.x*256 + threadIdx.x;
  if (idx >= NVIEWS*HALFT) return;
  const int v = idx / HALFT, t = idx % HALFT;
  float f = weights[t] * (1.0f/36864.0f);
  if (t != 0 && t != 192) f *= 2.0f;
  float o[8];
  if (t == 192) {
    #pragma unroll
    for (int cb = 0; cb < 4; ++cb) { o[2*cb] = f*dcsum[2*cb]; o[2*cb+1] = f*dcsum[2*cb+1]; }
  } else {
    #pragma unroll
    for (int cb = 0; cb < 4; ++cb) {
      float ar = 0.f, ai = 0.f;
      for (int s = 0; s < nsplit; ++s) {
        const float* p = kpart + (((s*NVIEWS + v)*192 + t)*4 + cb)*2;
        ar += p[0]; ai += p[1];
      }
      o[2*cb] = f*ar; o[2*cb+1] = f*ai;
    }
  }
  float* q = K2 + idx*8;
  #pragma unroll
  for (int j = 0; j < 8; ++j) q[j] = o[j];
}

template <int VPC>
__global__ __launch_bounds__(256) void adj_kernel(
    const float* __restrict__ K2, const float* __restrict__ points,
    float* __restrict__ imgpart) {
  const int pix = blockIdx.x*256 + threadIdx.x;
  const int chunk = blockIdx.y;
  const float nh = (float)(pix / WW - 96);
  const float nw = (float)(pix % WW - 96);
  float re[4] = {0,0,0,0}, im[4] = {0,0,0,0};
  const float INVPI = 0.3183098861837907f;
  const float PI192 = 3.14159265358979f / 192.0f;
  for (int v = chunk*VPC; v < chunk*VPC + VPC; ++v) {
    const float ct = -points[2*(v*NSAMP)+0] * INVPI;
    const float st = -points[2*(v*NSAMP)+1] * INVPI;
    const float alpha = ct*nh + st*nw;
    const float delta = alpha * PI192;
    float dr, di; __sincosf(delta, &di, &dr);
    float c0r, c0i; __sincosf(-192.0f*delta, &c0i, &c0r);
    const float* Kv = K2 + v*HALFT*8;
    #pragma unroll
    for (int cb = 0; cb < 4; ++cb) {
      float a = Kv[2*cb], b = Kv[2*cb+1];
      re[cb] += a*c0r - b*c0i;
      im[cb] += a*c0i + b*c0r;
    }
    float d2r = dr*dr - di*di, d2i = 2.0f*dr*di;
    float ar = c0r*dr - c0i*di, ai = c0r*di + c0i*dr;
    float br = ar*dr - ai*di,  bi = ar*di + ai*dr;
    for (int i = 0; i < 95; ++i) {
      const float* ka = Kv + (2*i+1)*8;
      const float* kb = Kv + (2*i+2)*8;
      #pragma unroll
      for (int cb = 0; cb < 4; ++cb)
        re[cb] += ka[2*cb]*ar - ka[2*cb+1]*ai;
      #pragma unroll
      for (int cb = 0; cb < 4; ++cb)
        re[cb] += kb[2*cb]*br - kb[2*cb+1]*bi;
      rot(ar, ai, d2r, d2i);
      rot(br, bi, d2r, d2i);
    }
    {
      const float* ka = Kv + 191*8;
      #pragma unroll
      for (int cb = 0; cb < 4; ++cb)
        re[cb] += ka[2*cb]*ar - ka[2*cb+1]*ai;
    }
    const float* kd = Kv + 192*8;
    #pragma unroll
    for (int cb = 0; cb < 4; ++cb) { re[cb] += kd[2*cb]; im[cb] += kd[2*cb+1]; }
  }
  float* o = imgpart + (chunk*NPIX + pix)*8;
  #pragma unroll
  for (int cb = 0; cb < 4; ++cb) { o[2*cb] = re[cb]; o[2*cb+1] = im[cb]; }
}

__global__ __launch_bounds__(256) void out_fb_kernel(
    const float* __restrict__ imgpart, float* __restrict__ out, int nchunk) {
  const int pix = blockIdx.x*256 + threadIdx.x;
  float re[4] = {0,0,0,0}, im[4] = {0,0,0,0};
  for (int ch = 0; ch < nchunk; ++ch) {
    const float* p = imgpart + (ch*NPIX + pix)*8;
    #pragma unroll
    for (int cb = 0; cb < 4; ++cb) { re[cb] += p[2*cb]; im[cb] += p[2*cb+1]; }
  }
  #pragma unroll
  for (int b = 0; b < 2; ++b)
    #pragma unroll
    for (int c = 0; c < 2; ++c) {
      const int cb = b*2 + c;
      out[(b*NPIX + pix)*2 + c] = sqrtf(re[cb]*re[cb] + im[cb]*im[cb]);
    }
}

extern "C" void kernel_launch(void* const* d_in, const int* in_sizes, int n_in,
                              void* d_out, int out_size, void* d_ws, size_t ws_size,
                              hipStream_t stream) {
  const float* x       = (const float*)d_in[0];
  const float* points  = (const float*)d_in[1];
  const float* weights = (const float*)d_in[2];
  float* out = (float*)d_out;

  const size_t NEED = 79265792ull;
  if (ws_size >= NEED) {
    char* wsb = (char*)d_ws;
    unsigned short* BT   = (unsigned short*)(wsb + 0);          //  9,732,096
    unsigned short* CxT  = (unsigned short*)(wsb + 9732096);    //  4,866,048
    unsigned short* SxT  = (unsigned short*)(wsb + 14598144);   //  4,866,048
    float* combos        = (float*)(wsb + 19464192);            //    811,008
    float* K2edge        = (float*)(wsb + 20275200);            //      8,192
    char* S              = wsb + 20283392;                      // 58,982,400
    // phase A
    unsigned short* Am   = (unsigned short*)(S + 0);            //  9,732,096
    unsigned short* XT   = (unsigned short*)(S + 9732096);      //    294,912
    float* Abuf          = (float*)(S + 10027008);              //    811,008
    // phase B (overlaps phase A; stream-ordered: Abuf consumed by combine2
    // before tmat overwrites the region)
    unsigned short* Aadj = (unsigned short*)(S + 0);            // 38,928,384
    float* partials      = (float*)(S + 38928384);              // 19,464,192
    float* imb           = (float*)(S + 58392576);              //    589,824

    phase_kernel<<<dim3(65,8), 256, 0, stream>>>(points, BT, CxT, SxT, Am);
    xprep_kernel<<<576, 256, 0, stream>>>(x, XT);
    gemm1_kernel<<<dim3(198,4), 256, 0, stream>>>(Am, XT, points, Abuf);
    combine2_kernel<<<(M2 + 255)/256, 256, 0, stream>>>(
        Abuf, weights, combos, K2edge);
    tmat_kernel<<<dim3((M2P + 255)/256, 768), 256, 0, stream>>>(
        combos, CxT, SxT, Aadj);
    adj_gemm<<<dim3(6, NSPLITK), 256, 0, stream>>>(Aadj, BT, partials);
    im_kernel<<<576, 256, 0, stream>>>(BT, CxT, SxT, K2edge, imb);
    out_new_kernel<<<(192*768)/256, 256, 0, stream>>>(partials, imb, out);
  } else {
    // r2 fallback path
    float* ws = (float*)d_ws;
    const size_t ws_floats = ws_size / sizeof(float);
    int nsplit = 16, nchunk = 16;
    auto need = [&](int ns, int nc) -> size_t {
      return (size_t)ns*196608 + 8 + 197632 + (size_t)nc*294912;
    };
    while (need(nsplit, nchunk) > ws_floats && nchunk > 1) nchunk >>= 1;
    while (need(nsplit, nchunk) > ws_floats && nsplit > 1) nsplit >>= 1;

    float* kpart   = ws;
    float* dcsum   = kpart + (size_t)nsplit*196608;
    float* K2      = dcsum + 8;
    float* imgpart = K2 + 197632;

    switch (nsplit) {
      case 16: fwd_kernel<12><<<dim3(NVIEWS,16), 192, 0, stream>>>(x, points, kpart); break;
      case 8:  fwd_kernel<24><<<dim3(NVIEWS,8),  192, 0, stream>>>(x, points, kpart); break;
      case 4:  fwd_kernel<48><<<dim3(NVIEWS,4),  192, 0, stream>>>(x, points, kpart); break;
      case 2:  fwd_kernel<96><<<dim3(NVIEWS,2),  192, 0, stream>>>(x, points, kpart); break;
      default: fwd_kernel<192><<<dim3(NVIEWS,1), 192, 0, stream>>>(x, points, kpart); break;
    }
    dc_kernel<<<1, 256, 0, stream>>>(x, dcsum);
    combine_kernel<<<(NVIEWS*HALFT + 255)/256, 256, 0, stream>>>(
        kpart, dcsum, weights, K2, nsplit);
    switch (nchunk) {
      case 16: adj_kernel<8>  <<<dim3(NPIX/256,16), 256, 0, stream>>>(K2, points, imgpart); break;
      case 8:  adj_kernel<16> <<<dim3(NPIX/256,8),  256, 0, stream>>>(K2, points, imgpart); break;
      case 4:  adj_kernel<32> <<<dim3(NPIX/256,4),  256, 0, stream>>>(K2, points, imgpart); break;
      case 2:  adj_kernel<64> <<<dim3(NPIX/256,2),  256, 0, stream>>>(K2, points, imgpart); break;
      default: adj_kernel<128><<<dim3(NPIX/256,1),  256, 0, stream>>>(K2, points, imgpart); break;
    }
    out_fb_kernel<<<NPIX/256, 256, 0, stream>>>(imgpart, out, nchunk);
  }
}